// Round 10
// baseline (31648.257 us; speedup 1.0000x reference)
//
#include <hip/hip_runtime.h>
#include <math.h>

#define TSTEPS 1024
#define NITER  1027

typedef __attribute__((ext_vector_type(8))) short s8v;   // bf16x8 MFMA frag
typedef __attribute__((ext_vector_type(4))) float f4v;   // f32x4 acc

// ---- ws byte offsets (identical to R9) ----
// W1F [16kt][64jt][2spl] 1KB frags ; W0F [9][64][2] ; FCF [8][16][2]
// H0P/H1P [2 parity][256 r][256 j] u32 = (bf16hi<<16)|bf16lo   (NOTE: now [r][j])
// B0S/B1S [256 jh][4 gate] f32 ; PB [2][16][256] f32 ; CNT barrier counter
#define OW1F 0u
#define OW0F 2097152u
#define OFCF 3276800u
#define OH0P 3538944u
#define OH1P 4063232u
#define OB0S 4587520u
#define OB1S 4591616u
#define OPB  4595712u
#define OCNT 4628480u

#define MFMA(A,B,C) __builtin_amdgcn_mfma_f32_16x16x32_bf16(A, B, C, 0, 0, 0)

__device__ __forceinline__ short bf_hi(float v) {
    unsigned u = __builtin_bit_cast(unsigned, v);
    unsigned r = (u + 0x7FFFu + ((u >> 16) & 1u)) >> 16;
    return (short)r;
}
__device__ __forceinline__ float bf_f(short h) {
    unsigned u = ((unsigned)(unsigned short)h) << 16;
    return __builtin_bit_cast(float, u);
}
__device__ __forceinline__ float fast_sigmoid(float v) {
    return __builtin_amdgcn_rcpf(1.0f + __expf(-v));
}
__device__ __forceinline__ float fast_tanh(float v) {
    return 1.0f - 2.0f * __builtin_amdgcn_rcpf(1.0f + __expf(2.0f * v));
}

// ---- prep: identical to R9 (validated) ----
#define NSH_W1 1048576u
#define NSH_W0 589824u
#define NSH_TOT 1769472u
#define NTAIL 273408u

__global__ __launch_bounds__(256) void prep_kernel(
    const float* __restrict__ Wih0, const float* __restrict__ Whh0,
    const float* __restrict__ bih0, const float* __restrict__ bhh0,
    const float* __restrict__ Wih1, const float* __restrict__ Whh1,
    const float* __restrict__ bih1, const float* __restrict__ bhh1,
    const float* __restrict__ fc1w,
    char* __restrict__ ws)
{
    const unsigned NTOT = NSH_TOT + NTAIL;
    for (unsigned idx = blockIdx.x * blockDim.x + threadIdx.x; idx < NTOT;
         idx += gridDim.x * blockDim.x) {
        if (idx < NSH_TOT) {
            unsigned i2, mode, off;
            if (idx < NSH_W1)               { i2 = idx;                  mode = 0; off = OW1F; }
            else if (idx < NSH_W1 + NSH_W0) { i2 = idx - NSH_W1;         mode = 1; off = OW0F; }
            else                            { i2 = idx - NSH_W1 - NSH_W0; mode = 2; off = OFCF; }
            unsigned frag = i2 >> 9, el = i2 & 511u;
            unsigned lane = el >> 3, e = el & 7u;
            unsigned spl = frag & 1u, jtw = frag >> 1;
            unsigned n = lane & 15u, g = lane >> 4;
            unsigned kw = 4u*g + (e & 3u) + ((e >> 2) << 4);
            float w = 0.f;
            if (mode == 2) {
                unsigned jt = jtw & 15u, kt = frag >> 5;
                unsigned row = jt*16u + n;
                w = fc1w[row*256u + kt*32u + kw];
            } else {
                unsigned jt = jtw & 63u, kt = frag >> 7;
                unsigned row = (n & 3u)*256u + jt*4u + (n >> 2);
                unsigned kg = kt*32u + kw;
                if (mode == 0) {
                    w = (kg < 256u) ? Wih1[row*256u + kg] : Whh1[row*256u + (kg - 256u)];
                } else {
                    if (kt == 0u) w = (kw < 16u) ? Wih0[row*16u + kw] : 0.f;
                    else          w = Whh0[row*256u + (kg - 32u)];
                }
            }
            short hv = bf_hi(w);
            short val = spl ? bf_hi(w - bf_f(hv)) : hv;
            *(short*)(ws + off + (size_t)frag*1024u + (size_t)el*2u) = val;
        } else {
            unsigned f = idx - NSH_TOT;
            if (f < 262144u) {
                ((unsigned*)(ws + OH0P))[f] = 0u;
            } else if (f < 263168u) {
                unsigned i3 = f - 262144u, jh = i3 >> 2, gq = i3 & 3u;
                ((float*)(ws + OB0S))[i3] = bih0[gq*256u + jh] + bhh0[gq*256u + jh];
            } else if (f < 264192u) {
                unsigned i3 = f - 263168u, jh = i3 >> 2, gq = i3 & 3u;
                ((float*)(ws + OB1S))[i3] = bih1[gq*256u + jh] + bhh1[gq*256u + jh];
            } else if (f < 272384u) {
                ((float*)(ws + OPB))[f - 264192u] = 0.f;
            } else {
                ((unsigned*)(ws + OCNT))[f - 272384u] = 0u;
            }
        }
    }
}

// A-frag pair load from [r][j] packed plane: lo quad = j KB+4g4.., hi quad = +16
#define LDH(LO, HI, PL, RT, KB) do { \
    const unsigned* bp_ = (PL) + ((unsigned)(RT)*16u + (unsigned)n15)*256u \
                               + (unsigned)(KB) + 4u*(unsigned)g4; \
    LO = *(const uint4*)bp_; HI = *(const uint4*)(bp_ + 16); \
  } while (0)

#define UNPK(AH, AL, LO, HI) do { \
    AH[0]=(short)((LO).x>>16); AH[1]=(short)((LO).y>>16); \
    AH[2]=(short)((LO).z>>16); AH[3]=(short)((LO).w>>16); \
    AH[4]=(short)((HI).x>>16); AH[5]=(short)((HI).y>>16); \
    AH[6]=(short)((HI).z>>16); AH[7]=(short)((HI).w>>16); \
    AL[0]=(short)((LO).x&0xffffu); AL[1]=(short)((LO).y&0xffffu); \
    AL[2]=(short)((LO).z&0xffffu); AL[3]=(short)((LO).w&0xffffu); \
    AL[4]=(short)((HI).x&0xffffu); AL[5]=(short)((HI).y&0xffffu); \
    AL[6]=(short)((HI).z&0xffffu); AL[7]=(short)((HI).w&0xffffu); \
  } while (0)

#define MFMA4(ACC, AH, AL, BH, BL) do { \
    ACC = MFMA(AH, BH, ACC); ACC = MFMA(AL, BH, ACC); \
    ACC = MFMA(AH, BL, ACC); ACC = MFMA(AL, BL, ACC); \
  } while (0)

// 256 blocks x 512 threads. Wave (wv 0..7): kh = wv&1 (K-half), rtl2 = (wv>>1)&1,
// jtl = wv>>2. Per wave: 1 jt x 2 rt x half-K. Partials joined via LDS.
// blocks [0,128): L1 step i-1 ; blocks [128,256): L0 step i + FC step i-2
// (+ block 128: out for step i-3).
template<bool ISL1>
__device__ __forceinline__ void role(
    const float* __restrict__ x,
    const float* __restrict__ fc1b, const float* __restrict__ fc2w,
    const float* __restrict__ fc2b,
    char* __restrict__ ws, float* __restrict__ out,
    int blk, int wv, int lane, float* red, float* fcs)
{
    const int tid  = wv*64 + lane;
    const int b    = blk & 127;
    const int kh   = wv & 1;
    const int rtl2 = (wv >> 1) & 1;
    const int jtl  = wv >> 2;
    const int jt   = (b >> 2)*2 + jtl;
    const int rt0w = (b & 3)*4 + rtl2*2;
    const int n15  = lane & 15, g4 = lane >> 4, q = lane & 3;
    const int jh   = jt*4 + (n15 >> 2);
    const int rx   = (jtl*2 + rtl2)*2;

    unsigned* const h0p = (unsigned*)(ws + OH0P);
    unsigned* const h1p = (unsigned*)(ws + OH1P);
    unsigned* const cnt = (unsigned*)(ws + OCNT);

    // stationary B-frags: 64 VGPRs max (8 tiles L1, 5 tiles L0-kh0)
    constexpr int NB = ISL1 ? 8 : 5;
    s8v Bh[NB], Bl[NB];
    {
        const char* wb = ws + (ISL1 ? OW1F : OW0F);
        const int nb = ISL1 ? 8 : (kh ? 4 : 5);
        #pragma unroll
        for (int t = 0; t < NB; ++t) {
            if (t < nb) {
                const int ktg = ISL1 ? (kh*8 + t) : (kh ? 5 + t : t);
                const char* fb = wb + ((size_t)(ktg*64 + jt)*2u)*1024u + (size_t)lane*16u;
                Bh[t] = *(const s8v*)fb;
                Bl[t] = *(const s8v*)(fb + 1024u);
            }
        }
    }
    const float4 bsv = *(const float4*)(ws + (ISL1 ? OB1S : OB0S) + (size_t)jh*16u);
    float c0[4] = {0,0,0,0}, c1[4] = {0,0,0,0};

    // FC setup (L0 blocks; wave wv owns fc-kt = wv)
    int fjt = 0, frt0 = 0;
    s8v Fh = {0,0,0,0,0,0,0,0}, Fl = {0,0,0,0,0,0,0,0};
    float fb1 = 0.f, fw2 = 0.f, f2b0 = 0.f;
    if (!ISL1) {
        fjt = b >> 3; frt0 = (b & 7)*2;
        const char* fb = ws + OFCF + ((size_t)(wv*16 + fjt)*2u)*1024u + (size_t)lane*16u;
        Fh = *(const s8v*)fb;
        Fl = *(const s8v*)(fb + 1024u);
        fb1  = fc1b[fjt*16 + n15];
        fw2  = fc2w[fjt*16 + n15];
        f2b0 = fc2b[0];
    }

    #pragma unroll 1
    for (int i = 0; i < NITER; ++i) {
        const int s = ISL1 ? (i - 1) : i;
        const bool act = (s >= 0) && (s < TSTEPS);
        f4v acc0 = {0,0,0,0}, acc1 = {0,0,0,0};

        // FC loads issued early (hide latency under LSTM compute)
        const int sf = i - 2;
        const bool fact = (!ISL1) && (sf >= 0) && (sf < TSTEPS);
        uint4 fl0 = {0,0,0,0}, fh0 = {0,0,0,0}, fl1 = {0,0,0,0}, fh1 = {0,0,0,0};
        if (fact) {
            const unsigned* pf = h1p + (unsigned)(sf & 1) * 65536u;
            LDH(fl0, fh0, pf, frt0,     wv*32);
            LDH(fl1, fh1, pf, frt0 + 1, wv*32);
        }

        if (act) {
            const unsigned* P;
            if (ISL1) P = kh ? (h1p + (unsigned)((s + 1) & 1) * 65536u)
                             : (h0p + (unsigned)(s & 1) * 65536u);
            else      P = h0p + (unsigned)((s + 1) & 1) * 65536u;

            uint4 hq[4][4];
            if (ISL1) {
                #pragma unroll
                for (int t = 0; t < 4; ++t) {
                    LDH(hq[t][0], hq[t][1], P, rt0w,     t*32);
                    LDH(hq[t][2], hq[t][3], P, rt0w + 1, t*32);
                }
                #pragma unroll
                for (int t = 0; t < 8; ++t) {
                    const int sl = t & 3;
                    s8v ah, al;
                    UNPK(ah, al, hq[sl][0], hq[sl][1]);
                    MFMA4(acc0, ah, al, Bh[t], Bl[t]);
                    UNPK(ah, al, hq[sl][2], hq[sl][3]);
                    MFMA4(acc1, ah, al, Bh[t], Bl[t]);
                    if (t + 4 < 8) {
                        LDH(hq[sl][0], hq[sl][1], P, rt0w,     (t+4)*32);
                        LDH(hq[sl][2], hq[sl][3], P, rt0w + 1, (t+4)*32);
                    }
                }
            } else {
                #pragma unroll
                for (int t = 0; t < 4; ++t) {
                    const int ktl = kh ? 4 + t : t;
                    LDH(hq[t][0], hq[t][1], P, rt0w,     ktl*32);
                    LDH(hq[t][2], hq[t][3], P, rt0w + 1, ktl*32);
                }
                if (!kh) {   // x-projection tile (B tile 0): [x(16) | 16 zero-pad]
                    #pragma unroll
                    for (int d = 0; d < 2; ++d) {
                        const int r = (rt0w + d)*16 + n15;
                        const float4 xv = *(const float4*)(x + ((size_t)r*TSTEPS + s)*16u
                                                             + 4u*(unsigned)g4);
                        float xs[4] = {xv.x, xv.y, xv.z, xv.w};
                        s8v ah, al;
                        #pragma unroll
                        for (int e = 0; e < 4; ++e) {
                            short hv2 = bf_hi(xs[e]);
                            ah[e] = hv2; al[e] = bf_hi(xs[e] - bf_f(hv2));
                            ah[e + 4] = 0; al[e + 4] = 0;
                        }
                        if (d == 0) MFMA4(acc0, ah, al, Bh[0], Bl[0]);
                        else        MFMA4(acc1, ah, al, Bh[0], Bl[0]);
                    }
                }
                #pragma unroll
                for (int t = 0; t < 4; ++t) {
                    const int bi = kh ? t : 1 + t;
                    s8v ah, al;
                    UNPK(ah, al, hq[t][0], hq[t][1]);
                    MFMA4(acc0, ah, al, Bh[bi], Bl[bi]);
                    UNPK(ah, al, hq[t][2], hq[t][3]);
                    MFMA4(acc1, ah, al, Bh[bi], Bl[bi]);
                }
            }
        }

        // ---- K-half partial exchange: kh1 -> kh0 ----
        if (act && kh) {
            *(f4v*)&red[(rx + 0)*256 + lane*4] = acc0;
            *(f4v*)&red[(rx + 1)*256 + lane*4] = acc1;
        }
        __syncthreads();
        if (act && !kh) {
            acc0 = acc0 + *(const f4v*)&red[(rx + 0)*256 + lane*4];
            acc1 = acc1 + *(const f4v*)&red[(rx + 1)*256 + lane*4];

            // cell update (gate quads within lane groups), store packed h
            unsigned* hwp = (ISL1 ? h1p : h0p) + (unsigned)(s & 1) * 65536u;
            #pragma unroll
            for (int d = 0; d < 2; ++d) {
                const int rt = rt0w + d;
                f4v av = d ? acc1 : acc0;
                float* cc = d ? c1 : c0;
                unsigned pk[4];
                #pragma unroll
                for (int e = 0; e < 4; ++e) {
                    float v0 = av[e];
                    float v1 = __shfl_xor(v0, 1);
                    float v2 = __shfl_xor(v0, 2);
                    float v3 = __shfl_xor(v1, 2);
                    float gi = (q==0)? v0 : (q==1)? v1 : (q==2)? v2 : v3;
                    float gf = (q==0)? v1 : (q==1)? v0 : (q==2)? v3 : v2;
                    float gg = (q==0)? v2 : (q==1)? v3 : (q==2)? v0 : v1;
                    float go = (q==0)? v3 : (q==1)? v2 : (q==2)? v1 : v0;
                    float ig = fast_sigmoid(gi + bsv.x);
                    float fg = fast_sigmoid(gf + bsv.y);
                    float gt = fast_tanh   (gg + bsv.z);
                    float og = fast_sigmoid(go + bsv.w);
                    float cn = fg * cc[e] + ig * gt;
                    cc[e] = cn;
                    float h = og * fast_tanh(cn);
                    short hv = bf_hi(h);
                    short lv = bf_hi(h - bf_f(hv));
                    pk[e] = ((unsigned)(unsigned short)hv << 16) | (unsigned)(unsigned short)lv;
                }
                if (q == 0) {
                    #pragma unroll
                    for (int e = 0; e < 4; ++e) {
                        const int r = rt*16 + 4*g4 + e;
                        __hip_atomic_store(hwp + (unsigned)r*256u + (unsigned)jh, pk[e],
                                           __ATOMIC_RELAXED, __HIP_MEMORY_SCOPE_AGENT);
                    }
                }
            }
        }

        if (!ISL1) {
            // ---- FC: fc1 + relu + fc2 partials for step i-2 ----
            if (fact) {
                f4v fa0 = {0,0,0,0}, fa1 = {0,0,0,0};
                s8v ah, al;
                UNPK(ah, al, fl0, fh0);
                MFMA4(fa0, ah, al, Fh, Fl);
                UNPK(ah, al, fl1, fh1);
                MFMA4(fa1, ah, al, Fh, Fl);
                *(f4v*)&fcs[(wv*2 + 0)*256 + lane*4] = fa0;
                *(f4v*)&fcs[(wv*2 + 1)*256 + lane*4] = fa1;
            }
            __syncthreads();
            if (fact && wv == 0) {
                #pragma unroll
                for (int d = 0; d < 2; ++d) {
                    f4v av = {0,0,0,0};
                    #pragma unroll
                    for (int w2 = 0; w2 < 8; ++w2)
                        av = av + *(const f4v*)&fcs[(w2*2 + d)*256 + lane*4];
                    float pe[4];
                    #pragma unroll
                    for (int e = 0; e < 4; ++e) {
                        float v = av[e] + fb1;
                        v = v > 0.f ? v : 0.f;
                        float p = v * fw2;
                        p += __shfl_xor(p, 1);
                        p += __shfl_xor(p, 2);
                        p += __shfl_xor(p, 4);
                        p += __shfl_xor(p, 8);
                        pe[e] = p;
                    }
                    if (n15 == 0) {
                        unsigned* pb = (unsigned*)(ws + OPB) + (unsigned)(i & 1)*4096u
                                       + (unsigned)(fjt*256 + (frt0 + d)*16 + 4*g4);
                        unsigned long long lo =
                            ((unsigned long long)__builtin_bit_cast(unsigned, pe[1]) << 32)
                            | __builtin_bit_cast(unsigned, pe[0]);
                        unsigned long long hi =
                            ((unsigned long long)__builtin_bit_cast(unsigned, pe[3]) << 32)
                            | __builtin_bit_cast(unsigned, pe[2]);
                        __hip_atomic_store((unsigned long long*)pb,       lo, __ATOMIC_RELAXED, __HIP_MEMORY_SCOPE_AGENT);
                        __hip_atomic_store((unsigned long long*)(pb + 2), hi, __ATOMIC_RELAXED, __HIP_MEMORY_SCOPE_AGENT);
                    }
                }
            }
            // ---- out: final fc2 reduce for step i-3 (block 128 only) ----
            if (b == 0 && i >= 3 && tid < 256) {
                const int tt = i - 3;
                const float* pb2 = (const float*)(ws + OPB) + (unsigned)((i - 1) & 1)*4096u;
                float ssum = f2b0;
                #pragma unroll
                for (int jx = 0; jx < 16; ++jx) ssum += pb2[jx*256 + tid];
                __hip_atomic_store((unsigned*)&out[(size_t)tid*TSTEPS + tt],
                                   __builtin_bit_cast(unsigned, ssum),
                                   __ATOMIC_RELAXED, __HIP_MEMORY_SCOPE_AGENT);
            }
        }

        // ---- lightweight grid barrier (R9-validated) ----
        __syncthreads();
        if (tid == 0) {
            __hip_atomic_fetch_add(cnt, 1u, __ATOMIC_RELAXED, __HIP_MEMORY_SCOPE_AGENT);
            const unsigned tgt = 256u * (unsigned)(i + 1);
            while (__hip_atomic_load(cnt, __ATOMIC_RELAXED, __HIP_MEMORY_SCOPE_AGENT) < tgt)
                __builtin_amdgcn_s_sleep(2);
        }
        __syncthreads();
        __builtin_amdgcn_fence(__ATOMIC_ACQUIRE, "agent");
    }
}

__global__ __launch_bounds__(512, 2) void lstm_mfma(
    const float* __restrict__ x, const float* __restrict__ fc1b,
    const float* __restrict__ fc2w, const float* __restrict__ fc2b,
    char* __restrict__ ws, float* __restrict__ out)
{
    __shared__ __align__(16) float red[2048];
    __shared__ __align__(16) float fcs[4096];
    const int tid  = threadIdx.x;
    const int lane = tid & 63;
    const int wv   = __builtin_amdgcn_readfirstlane(tid >> 6);
    const int blk  = blockIdx.x;
    if (blk < 128) role<true >(x, fc1b, fc2w, fc2b, ws, out, blk, wv, lane, red, fcs);
    else           role<false>(x, fc1b, fc2w, fc2b, ws, out, blk, wv, lane, red, fcs);
}

extern "C" void kernel_launch(void* const* d_in, const int* in_sizes, int n_in,
                              void* d_out, int out_size, void* d_ws, size_t ws_size,
                              hipStream_t stream)
{
    const float* x    = (const float*)d_in[0];
    const float* Wih0 = (const float*)d_in[1];
    const float* Whh0 = (const float*)d_in[2];
    const float* bih0 = (const float*)d_in[3];
    const float* bhh0 = (const float*)d_in[4];
    const float* Wih1 = (const float*)d_in[5];
    const float* Whh1 = (const float*)d_in[6];
    const float* bih1 = (const float*)d_in[7];
    const float* bhh1 = (const float*)d_in[8];
    const float* fc1w = (const float*)d_in[9];
    const float* fc1b = (const float*)d_in[10];
    const float* fc2w = (const float*)d_in[11];
    const float* fc2b = (const float*)d_in[12];
    char*  ws  = (char*)d_ws;
    float* out = (float*)d_out;

    prep_kernel<<<1024, 256, 0, stream>>>(Wih0, Whh0, bih0, bhh0,
                                          Wih1, Whh1, bih1, bhh1, fc1w, ws);

    void* args[] = {(void*)&x, (void*)&fc1b, (void*)&fc2w, (void*)&fc2b,
                    (void*)&ws, (void*)&out};
    hipLaunchCooperativeKernel((const void*)lstm_mfma, dim3(256), dim3(512),
                               args, 0, stream);
}

// Round 11
// 24330.835 us; speedup vs baseline: 1.3007x; 1.3007x over previous
//
#include <hip/hip_runtime.h>
#include <math.h>

#define TSTEPS 1024
#define NITER  1027

typedef __attribute__((ext_vector_type(8))) short s8v;   // bf16x8 MFMA frag
typedef __attribute__((ext_vector_type(4))) float f4v;   // f32x4 acc

// ---- ws byte offsets ----
// W1F [16kt][64jt][2spl] 1KB frags ; W0F [9][64][2] ; FCF [8][16][2]
// H0P/H1P [2 parity][256 r][256 j] u32 = (bf16hi<<16)|bf16lo
// B0S/B1S [256 jh][4 gate] f32 ; PB [2][16][256] f32 ; CNT barrier counter
#define OW1F 0u
#define OW0F 2097152u
#define OFCF 3276800u
#define OH0P 3538944u
#define OH1P 4063232u
#define OB0S 4587520u
#define OB1S 4591616u
#define OPB  4595712u
#define OCNT 4628480u

#define MFMA(A,B,C) __builtin_amdgcn_mfma_f32_16x16x32_bf16(A, B, C, 0, 0, 0)

__device__ __forceinline__ short bf_hi(float v) {
    unsigned u = __builtin_bit_cast(unsigned, v);
    unsigned r = (u + 0x7FFFu + ((u >> 16) & 1u)) >> 16;
    return (short)r;
}
__device__ __forceinline__ float bf_f(short h) {
    unsigned u = ((unsigned)(unsigned short)h) << 16;
    return __builtin_bit_cast(float, u);
}
__device__ __forceinline__ float fast_sigmoid(float v) {
    return __builtin_amdgcn_rcpf(1.0f + __expf(-v));
}
__device__ __forceinline__ float fast_tanh(float v) {
    return 1.0f - 2.0f * __builtin_amdgcn_rcpf(1.0f + __expf(2.0f * v));
}

// ---- prep: identical to R9/R10 (validated) ----
#define NSH_W1 1048576u
#define NSH_W0 589824u
#define NSH_TOT 1769472u
#define NTAIL 273408u

__global__ __launch_bounds__(256) void prep_kernel(
    const float* __restrict__ Wih0, const float* __restrict__ Whh0,
    const float* __restrict__ bih0, const float* __restrict__ bhh0,
    const float* __restrict__ Wih1, const float* __restrict__ Whh1,
    const float* __restrict__ bih1, const float* __restrict__ bhh1,
    const float* __restrict__ fc1w,
    char* __restrict__ ws)
{
    const unsigned NTOT = NSH_TOT + NTAIL;
    for (unsigned idx = blockIdx.x * blockDim.x + threadIdx.x; idx < NTOT;
         idx += gridDim.x * blockDim.x) {
        if (idx < NSH_TOT) {
            unsigned i2, mode, off;
            if (idx < NSH_W1)               { i2 = idx;                  mode = 0; off = OW1F; }
            else if (idx < NSH_W1 + NSH_W0) { i2 = idx - NSH_W1;         mode = 1; off = OW0F; }
            else                            { i2 = idx - NSH_W1 - NSH_W0; mode = 2; off = OFCF; }
            unsigned frag = i2 >> 9, el = i2 & 511u;
            unsigned lane = el >> 3, e = el & 7u;
            unsigned spl = frag & 1u, jtw = frag >> 1;
            unsigned n = lane & 15u, g = lane >> 4;
            unsigned kw = 4u*g + (e & 3u) + ((e >> 2) << 4);
            float w = 0.f;
            if (mode == 2) {
                unsigned jt = jtw & 15u, kt = frag >> 5;
                unsigned row = jt*16u + n;
                w = fc1w[row*256u + kt*32u + kw];
            } else {
                unsigned jt = jtw & 63u, kt = frag >> 7;
                unsigned row = (n & 3u)*256u + jt*4u + (n >> 2);
                unsigned kg = kt*32u + kw;
                if (mode == 0) {
                    w = (kg < 256u) ? Wih1[row*256u + kg] : Whh1[row*256u + (kg - 256u)];
                } else {
                    if (kt == 0u) w = (kw < 16u) ? Wih0[row*16u + kw] : 0.f;
                    else          w = Whh0[row*256u + (kg - 32u)];
                }
            }
            short hv = bf_hi(w);
            short val = spl ? bf_hi(w - bf_f(hv)) : hv;
            *(short*)(ws + off + (size_t)frag*1024u + (size_t)el*2u) = val;
        } else {
            unsigned f = idx - NSH_TOT;
            if (f < 262144u) {
                ((unsigned*)(ws + OH0P))[f] = 0u;
            } else if (f < 263168u) {
                unsigned i3 = f - 262144u, jh = i3 >> 2, gq = i3 & 3u;
                ((float*)(ws + OB0S))[i3] = bih0[gq*256u + jh] + bhh0[gq*256u + jh];
            } else if (f < 264192u) {
                unsigned i3 = f - 263168u, jh = i3 >> 2, gq = i3 & 3u;
                ((float*)(ws + OB1S))[i3] = bih1[gq*256u + jh] + bhh1[gq*256u + jh];
            } else if (f < 272384u) {
                ((float*)(ws + OPB))[f - 264192u] = 0.f;
            } else {
                ((unsigned*)(ws + OCNT))[f - 272384u] = 0u;
            }
        }
    }
}

// A-frag pair load from [r][j] packed plane (KB = k-base in u32)
#define LDH(LO, HI, PL, RT, KB) do { \
    const unsigned* bp_ = (PL) + ((unsigned)(RT)*16u + (unsigned)n15)*256u \
                               + (unsigned)(KB) + 4u*(unsigned)g4; \
    LO = *(const uint4*)bp_; HI = *(const uint4*)(bp_ + 16); \
  } while (0)

#define UNPK(AH, AL, LO, HI) do { \
    AH[0]=(short)((LO).x>>16); AH[1]=(short)((LO).y>>16); \
    AH[2]=(short)((LO).z>>16); AH[3]=(short)((LO).w>>16); \
    AH[4]=(short)((HI).x>>16); AH[5]=(short)((HI).y>>16); \
    AH[6]=(short)((HI).z>>16); AH[7]=(short)((HI).w>>16); \
    AL[0]=(short)((LO).x&0xffffu); AL[1]=(short)((LO).y&0xffffu); \
    AL[2]=(short)((LO).z&0xffffu); AL[3]=(short)((LO).w&0xffffu); \
    AL[4]=(short)((HI).x&0xffffu); AL[5]=(short)((HI).y&0xffffu); \
    AL[6]=(short)((HI).z&0xffffu); AL[7]=(short)((HI).w&0xffffu); \
  } while (0)

#define MFMA4(ACC, AH, AL, BH, BL) do { \
    ACC = MFMA(AH, BH, ACC); ACC = MFMA(AL, BH, ACC); \
    ACC = MFMA(AH, BL, ACC); ACC = MFMA(AL, BL, ACC); \
  } while (0)

// 256 blocks x 256 threads (4 waves). Wave: jtl = wv>>1, rtl = wv&1 ->
// one jt, two rt, FULL K (no intra-block LSTM exchange).
// blocks [0,128): L1 step i-1 ; [128,256): L0 step i + FC step i-2
// (+ block 128: out for step i-3). Weights LDS-stationary (staged once).
template<bool ISL1>
__device__ __forceinline__ void role(
    const float* __restrict__ x,
    const float* __restrict__ fc1b, const float* __restrict__ fc2w,
    const float* __restrict__ fc2b,
    char* __restrict__ ws, float* __restrict__ out,
    int blk, int wv, int lane, char* sm)
{
    const int tid  = wv*64 + lane;
    const int b    = blk & 127;
    const int jtl  = wv >> 1;
    const int rtl  = wv & 1;
    const int jbase = (b >> 2) * 2;
    const int jt   = jbase + jtl;
    const int rt0w = (b & 3)*4 + rtl*2;
    const int n15  = lane & 15, g4 = lane >> 4, q = lane & 3;
    const int jh   = jt*4 + (n15 >> 2);

    unsigned* const h0p = (unsigned*)(ws + OH0P);
    unsigned* const h1p = (unsigned*)(ws + OH1P);
    unsigned* const cnt = (unsigned*)(ws + OCNT);

    const int fjt = b >> 3, frt0 = (b & 7)*2;

    // ---- stage weights into LDS once ----
    if (ISL1) {
        // [jtl(2)][kt(16)][spl(2)] 1KB frags = 64KB
        for (int idx = tid; idx < 4096; idx += 256) {
            const int f = idx >> 6, inner = (idx & 63) << 4;
            const int jt2 = f >> 5, kt = (f >> 1) & 15, spl = f & 1;
            const char* src = ws + OW1F
                + ((size_t)((kt*64 + jbase + jt2)*2 + spl))*1024u + (unsigned)inner;
            *(uint4*)(sm + ((size_t)f << 10) + inner) = *(const uint4*)src;
        }
    } else {
        // [jtl(2)][kt(9)][spl(2)] = 36KB ; FC [kt(8)][spl(2)] at 36KB = 16KB
        for (int idx = tid; idx < 3328; idx += 256) {
            const int f = idx >> 6, inner = (idx & 63) << 4;
            const char* src;
            if (f < 36) {
                const int jt2 = f / 18, r2 = f - jt2*18, kt = r2 >> 1, spl = r2 & 1;
                src = ws + OW0F
                    + ((size_t)((kt*64 + jbase + jt2)*2 + spl))*1024u + (unsigned)inner;
            } else {
                const int f2 = f - 36, kt = f2 >> 1, spl = f2 & 1;
                src = ws + OFCF
                    + ((size_t)((kt*16 + fjt)*2 + spl))*1024u + (unsigned)inner;
            }
            *(uint4*)(sm + ((size_t)f << 10) + inner) = *(const uint4*)src;
        }
    }
    const char* wlw = sm + ((size_t)jtl * (ISL1 ? 32u : 18u)) * 1024u;
    const char* fcw = sm + 36864u;                 // L0 only
    float* fcs = (float*)(sm + 53248u);            // L0 only, 8KB
    __syncthreads();

    const float4 bsv = *(const float4*)(ws + (ISL1 ? OB1S : OB0S) + (size_t)jh*16u);
    float c0[4] = {0,0,0,0}, c1[4] = {0,0,0,0};
    float fb1 = 0.f, fw2 = 0.f, f2b0 = 0.f;
    if (!ISL1) {
        fb1  = fc1b[fjt*16 + n15];
        fw2  = fc2w[fjt*16 + n15];
        f2b0 = fc2b[0];
    }

    #pragma unroll 1
    for (int i = 0; i < NITER; ++i) {
        const int s = ISL1 ? (i - 1) : i;
        const bool act = (s >= 0) && (s < TSTEPS);
        f4v acc0 = {0,0,0,0}, acc1 = {0,0,0,0};

        // FC h-loads issued early (hide under LSTM compute)
        const int sf = i - 2;
        const bool fact = (!ISL1) && (sf >= 0) && (sf < TSTEPS);
        uint4 fq[2][4];
        if (fact) {
            const unsigned* pf = h1p + (unsigned)(sf & 1) * 65536u;
            #pragma unroll
            for (int kl = 0; kl < 2; ++kl) {
                const int ktf = 2*wv + kl;
                LDH(fq[kl][0], fq[kl][1], pf, frt0,     ktf*32);
                LDH(fq[kl][2], fq[kl][3], pf, frt0 + 1, ktf*32);
            }
        }

        if (act) {
            uint4 hq[4][4];
            if (ISL1) {
                const unsigned* P0 = h0p + (unsigned)(s & 1) * 65536u;        // h0(s)
                const unsigned* P1 = h1p + (unsigned)((s + 1) & 1) * 65536u;  // h1(s-1)
                #pragma unroll
                for (int t = 0; t < 4; ++t) {
                    LDH(hq[t][0], hq[t][1], P0, rt0w,     t*32);
                    LDH(hq[t][2], hq[t][3], P0, rt0w + 1, t*32);
                }
                #pragma unroll
                for (int t = 0; t < 16; ++t) {
                    const int sl = t & 3;
                    s8v bh = *(const s8v*)(wlw + ((size_t)(t*2)    << 10) + (size_t)lane*16u);
                    s8v bl = *(const s8v*)(wlw + ((size_t)(t*2 + 1) << 10) + (size_t)lane*16u);
                    s8v ah, al;
                    UNPK(ah, al, hq[sl][0], hq[sl][1]);
                    MFMA4(acc0, ah, al, bh, bl);
                    UNPK(ah, al, hq[sl][2], hq[sl][3]);
                    MFMA4(acc1, ah, al, bh, bl);
                    if (t + 4 < 16) {
                        const int kn = t + 4;
                        const unsigned* Pn = (kn < 8) ? P0 : P1;
                        const int cb = (kn & 7) * 32;
                        LDH(hq[sl][0], hq[sl][1], Pn, rt0w,     cb);
                        LDH(hq[sl][2], hq[sl][3], Pn, rt0w + 1, cb);
                    }
                }
            } else {
                const unsigned* P0 = h0p + (unsigned)((s + 1) & 1) * 65536u;  // h0(s-1)
                #pragma unroll
                for (int t = 0; t < 4; ++t) {
                    LDH(hq[t][0], hq[t][1], P0, rt0w,     t*32);
                    LDH(hq[t][2], hq[t][3], P0, rt0w + 1, t*32);
                }
                {   // x-projection: B tile 0 = [x(16) | zero-pad]
                    s8v bh = *(const s8v*)(wlw + (size_t)lane*16u);
                    s8v bl = *(const s8v*)(wlw + 1024u + (size_t)lane*16u);
                    #pragma unroll
                    for (int d = 0; d < 2; ++d) {
                        const int r = (rt0w + d)*16 + n15;
                        const float4 xv = *(const float4*)(x + ((size_t)r*TSTEPS + s)*16u
                                                             + 4u*(unsigned)g4);
                        float xs[4] = {xv.x, xv.y, xv.z, xv.w};
                        s8v ah, al;
                        #pragma unroll
                        for (int e = 0; e < 4; ++e) {
                            short hv2 = bf_hi(xs[e]);
                            ah[e] = hv2; al[e] = bf_hi(xs[e] - bf_f(hv2));
                            ah[e + 4] = 0; al[e + 4] = 0;
                        }
                        if (d == 0) MFMA4(acc0, ah, al, bh, bl);
                        else        MFMA4(acc1, ah, al, bh, bl);
                    }
                }
                #pragma unroll
                for (int t = 0; t < 8; ++t) {
                    const int sl = t & 3;
                    s8v bh = *(const s8v*)(wlw + ((size_t)((t+1)*2)     << 10) + (size_t)lane*16u);
                    s8v bl = *(const s8v*)(wlw + ((size_t)((t+1)*2 + 1) << 10) + (size_t)lane*16u);
                    s8v ah, al;
                    UNPK(ah, al, hq[sl][0], hq[sl][1]);
                    MFMA4(acc0, ah, al, bh, bl);
                    UNPK(ah, al, hq[sl][2], hq[sl][3]);
                    MFMA4(acc1, ah, al, bh, bl);
                    if (t + 4 < 8) {
                        const int cb = (t + 4) * 32;
                        LDH(hq[sl][0], hq[sl][1], P0, rt0w,     cb);
                        LDH(hq[sl][2], hq[sl][3], P0, rt0w + 1, cb);
                    }
                }
            }

            // ---- cell update (gate quads), store packed h [r][j] ----
            unsigned* hwp = (ISL1 ? h1p : h0p) + (unsigned)(s & 1) * 65536u;
            #pragma unroll
            for (int d = 0; d < 2; ++d) {
                const int rt = rt0w + d;
                f4v av = d ? acc1 : acc0;
                float* cc = d ? c1 : c0;
                unsigned pk[4];
                #pragma unroll
                for (int e = 0; e < 4; ++e) {
                    float v0 = av[e];
                    float v1 = __shfl_xor(v0, 1);
                    float v2 = __shfl_xor(v0, 2);
                    float v3 = __shfl_xor(v1, 2);
                    float gi = (q==0)? v0 : (q==1)? v1 : (q==2)? v2 : v3;
                    float gf = (q==0)? v1 : (q==1)? v0 : (q==2)? v3 : v2;
                    float gg = (q==0)? v2 : (q==1)? v3 : (q==2)? v0 : v1;
                    float go = (q==0)? v3 : (q==1)? v2 : (q==2)? v1 : v0;
                    float ig = fast_sigmoid(gi + bsv.x);
                    float fg = fast_sigmoid(gf + bsv.y);
                    float gt = fast_tanh   (gg + bsv.z);
                    float og = fast_sigmoid(go + bsv.w);
                    float cn = fg * cc[e] + ig * gt;
                    cc[e] = cn;
                    float h = og * fast_tanh(cn);
                    short hv = bf_hi(h);
                    short lv = bf_hi(h - bf_f(hv));
                    pk[e] = ((unsigned)(unsigned short)hv << 16) | (unsigned)(unsigned short)lv;
                }
                if (q == 0) {
                    #pragma unroll
                    for (int e = 0; e < 4; ++e) {
                        const int r = rt*16 + 4*g4 + e;
                        __hip_atomic_store(hwp + (unsigned)r*256u + (unsigned)jh, pk[e],
                                           __ATOMIC_RELAXED, __HIP_MEMORY_SCOPE_AGENT);
                    }
                }
            }
        }

        if (!ISL1) {
            // ---- FC: fc1 + relu + fc2 partials for step i-2 ----
            if (fact) {
                f4v fa0 = {0,0,0,0}, fa1 = {0,0,0,0};
                #pragma unroll
                for (int kl = 0; kl < 2; ++kl) {
                    const int ktf = 2*wv + kl;
                    s8v fh = *(const s8v*)(fcw + ((size_t)(ktf*2)     << 10) + (size_t)lane*16u);
                    s8v fl = *(const s8v*)(fcw + ((size_t)(ktf*2 + 1) << 10) + (size_t)lane*16u);
                    s8v ah, al;
                    UNPK(ah, al, fq[kl][0], fq[kl][1]);
                    MFMA4(fa0, ah, al, fh, fl);
                    UNPK(ah, al, fq[kl][2], fq[kl][3]);
                    MFMA4(fa1, ah, al, fh, fl);
                }
                *(f4v*)&fcs[(wv*2 + 0)*256 + lane*4] = fa0;
                *(f4v*)&fcs[(wv*2 + 1)*256 + lane*4] = fa1;
            }
            __syncthreads();
            if (fact && wv == 0) {
                #pragma unroll
                for (int d = 0; d < 2; ++d) {
                    f4v av = {0,0,0,0};
                    #pragma unroll
                    for (int w2 = 0; w2 < 4; ++w2)
                        av = av + *(const f4v*)&fcs[(w2*2 + d)*256 + lane*4];
                    float pe[4];
                    #pragma unroll
                    for (int e = 0; e < 4; ++e) {
                        float v = av[e] + fb1;
                        v = v > 0.f ? v : 0.f;
                        float p = v * fw2;
                        p += __shfl_xor(p, 1);
                        p += __shfl_xor(p, 2);
                        p += __shfl_xor(p, 4);
                        p += __shfl_xor(p, 8);
                        pe[e] = p;
                    }
                    if (n15 == 0) {
                        unsigned* pb = (unsigned*)(ws + OPB) + (unsigned)(i & 1)*4096u
                                       + (unsigned)(fjt*256 + (frt0 + d)*16 + 4*g4);
                        unsigned long long lo =
                            ((unsigned long long)__builtin_bit_cast(unsigned, pe[1]) << 32)
                            | __builtin_bit_cast(unsigned, pe[0]);
                        unsigned long long hi =
                            ((unsigned long long)__builtin_bit_cast(unsigned, pe[3]) << 32)
                            | __builtin_bit_cast(unsigned, pe[2]);
                        __hip_atomic_store((unsigned long long*)pb,       lo, __ATOMIC_RELAXED, __HIP_MEMORY_SCOPE_AGENT);
                        __hip_atomic_store((unsigned long long*)(pb + 2), hi, __ATOMIC_RELAXED, __HIP_MEMORY_SCOPE_AGENT);
                    }
                }
            }
            // ---- out: final fc2 reduce for step i-3 (block 128 only) ----
            if (b == 0 && i >= 3) {
                const int tt = i - 3;
                const float* pb2 = (const float*)(ws + OPB) + (unsigned)((i - 1) & 1)*4096u;
                float ssum = f2b0;
                #pragma unroll
                for (int jx = 0; jx < 16; ++jx) ssum += pb2[jx*256 + tid];
                __hip_atomic_store((unsigned*)&out[(size_t)tid*TSTEPS + tt],
                                   __builtin_bit_cast(unsigned, ssum),
                                   __ATOMIC_RELAXED, __HIP_MEMORY_SCOPE_AGENT);
            }
        }

        // ---- lightweight grid barrier (R9-validated) ----
        __syncthreads();
        if (tid == 0) {
            __hip_atomic_fetch_add(cnt, 1u, __ATOMIC_RELAXED, __HIP_MEMORY_SCOPE_AGENT);
            const unsigned tgt = 256u * (unsigned)(i + 1);
            while (__hip_atomic_load(cnt, __ATOMIC_RELAXED, __HIP_MEMORY_SCOPE_AGENT) < tgt)
                __builtin_amdgcn_s_sleep(2);
        }
        __syncthreads();
        __builtin_amdgcn_fence(__ATOMIC_ACQUIRE, "agent");
    }
}

__global__ __launch_bounds__(256, 1) void lstm_mfma(
    const float* __restrict__ x, const float* __restrict__ fc1b,
    const float* __restrict__ fc2w, const float* __restrict__ fc2b,
    char* __restrict__ ws, float* __restrict__ out)
{
    __shared__ __align__(16) char sm[65536];
    const int tid  = threadIdx.x;
    const int lane = tid & 63;
    const int wv   = __builtin_amdgcn_readfirstlane(tid >> 6);
    const int blk  = blockIdx.x;
    if (blk < 128) role<true >(x, fc1b, fc2w, fc2b, ws, out, blk, wv, lane, sm);
    else           role<false>(x, fc1b, fc2w, fc2b, ws, out, blk, wv, lane, sm);
}

extern "C" void kernel_launch(void* const* d_in, const int* in_sizes, int n_in,
                              void* d_out, int out_size, void* d_ws, size_t ws_size,
                              hipStream_t stream)
{
    const float* x    = (const float*)d_in[0];
    const float* Wih0 = (const float*)d_in[1];
    const float* Whh0 = (const float*)d_in[2];
    const float* bih0 = (const float*)d_in[3];
    const float* bhh0 = (const float*)d_in[4];
    const float* Wih1 = (const float*)d_in[5];
    const float* Whh1 = (const float*)d_in[6];
    const float* bih1 = (const float*)d_in[7];
    const float* bhh1 = (const float*)d_in[8];
    const float* fc1w = (const float*)d_in[9];
    const float* fc1b = (const float*)d_in[10];
    const float* fc2w = (const float*)d_in[11];
    const float* fc2b = (const float*)d_in[12];
    char*  ws  = (char*)d_ws;
    float* out = (float*)d_out;

    prep_kernel<<<1024, 256, 0, stream>>>(Wih0, Whh0, bih0, bhh0,
                                          Wih1, Whh1, bih1, bhh1, fc1w, ws);

    void* args[] = {(void*)&x, (void*)&fc1b, (void*)&fc2w, (void*)&fc2b,
                    (void*)&ws, (void*)&out};
    hipLaunchCooperativeKernel((const void*)lstm_mfma, dim3(256), dim3(256),
                               args, 0, stream);
}

// Round 12
// 20356.013 us; speedup vs baseline: 1.5547x; 1.1953x over previous
//
#include <hip/hip_runtime.h>
#include <math.h>

#define TSTEPS 1024
#define NITER  1027

typedef __attribute__((ext_vector_type(8))) short s8v;   // bf16x8 MFMA frag
typedef __attribute__((ext_vector_type(4))) float f4v;   // f32x4 acc

// ---- ws byte offsets ----
// W1F [16kt][64jt][2spl] 1KB frags ; W0F [9][64][2] ; FCF [8][16][2]
// H0P/H1P [2 parity][256 r][256 j] u32 = (bf16hi<<16)|bf16lo
// B0S/B1S [256 jh][4 gate] f32 ; PB [2][16][256] f32 ; CNT[0]=arrivals, CNT[16]=epoch
#define OW1F 0u
#define OW0F 2097152u
#define OFCF 3276800u
#define OH0P 3538944u
#define OH1P 4063232u
#define OB0S 4587520u
#define OB1S 4591616u
#define OPB  4595712u
#define OCNT 4628480u

#define MFMA(A,B,C) __builtin_amdgcn_mfma_f32_16x16x32_bf16(A, B, C, 0, 0, 0)

__device__ __forceinline__ short bf_hi(float v) {
    unsigned u = __builtin_bit_cast(unsigned, v);
    unsigned r = (u + 0x7FFFu + ((u >> 16) & 1u)) >> 16;
    return (short)r;
}
__device__ __forceinline__ float bf_f(short h) {
    unsigned u = ((unsigned)(unsigned short)h) << 16;
    return __builtin_bit_cast(float, u);
}
__device__ __forceinline__ float fast_sigmoid(float v) {
    return __builtin_amdgcn_rcpf(1.0f + __expf(-v));
}
__device__ __forceinline__ float fast_tanh(float v) {
    return 1.0f - 2.0f * __builtin_amdgcn_rcpf(1.0f + __expf(2.0f * v));
}

// ---- prep: identical to R9-R11 (validated) ----
#define NSH_W1 1048576u
#define NSH_W0 589824u
#define NSH_TOT 1769472u
#define NTAIL 273408u

__global__ __launch_bounds__(256) void prep_kernel(
    const float* __restrict__ Wih0, const float* __restrict__ Whh0,
    const float* __restrict__ bih0, const float* __restrict__ bhh0,
    const float* __restrict__ Wih1, const float* __restrict__ Whh1,
    const float* __restrict__ bih1, const float* __restrict__ bhh1,
    const float* __restrict__ fc1w,
    char* __restrict__ ws)
{
    const unsigned NTOT = NSH_TOT + NTAIL;
    for (unsigned idx = blockIdx.x * blockDim.x + threadIdx.x; idx < NTOT;
         idx += gridDim.x * blockDim.x) {
        if (idx < NSH_TOT) {
            unsigned i2, mode, off;
            if (idx < NSH_W1)               { i2 = idx;                  mode = 0; off = OW1F; }
            else if (idx < NSH_W1 + NSH_W0) { i2 = idx - NSH_W1;         mode = 1; off = OW0F; }
            else                            { i2 = idx - NSH_W1 - NSH_W0; mode = 2; off = OFCF; }
            unsigned frag = i2 >> 9, el = i2 & 511u;
            unsigned lane = el >> 3, e = el & 7u;
            unsigned spl = frag & 1u, jtw = frag >> 1;
            unsigned n = lane & 15u, g = lane >> 4;
            unsigned kw = 4u*g + (e & 3u) + ((e >> 2) << 4);
            float w = 0.f;
            if (mode == 2) {
                unsigned jt = jtw & 15u, kt = frag >> 5;
                unsigned row = jt*16u + n;
                w = fc1w[row*256u + kt*32u + kw];
            } else {
                unsigned jt = jtw & 63u, kt = frag >> 7;
                unsigned row = (n & 3u)*256u + jt*4u + (n >> 2);
                unsigned kg = kt*32u + kw;
                if (mode == 0) {
                    w = (kg < 256u) ? Wih1[row*256u + kg] : Whh1[row*256u + (kg - 256u)];
                } else {
                    if (kt == 0u) w = (kw < 16u) ? Wih0[row*16u + kw] : 0.f;
                    else          w = Whh0[row*256u + (kg - 32u)];
                }
            }
            short hv = bf_hi(w);
            short val = spl ? bf_hi(w - bf_f(hv)) : hv;
            *(short*)(ws + off + (size_t)frag*1024u + (size_t)el*2u) = val;
        } else {
            unsigned f = idx - NSH_TOT;
            if (f < 262144u) {
                ((unsigned*)(ws + OH0P))[f] = 0u;
            } else if (f < 263168u) {
                unsigned i3 = f - 262144u, jh = i3 >> 2, gq = i3 & 3u;
                ((float*)(ws + OB0S))[i3] = bih0[gq*256u + jh] + bhh0[gq*256u + jh];
            } else if (f < 264192u) {
                unsigned i3 = f - 263168u, jh = i3 >> 2, gq = i3 & 3u;
                ((float*)(ws + OB1S))[i3] = bih1[gq*256u + jh] + bhh1[gq*256u + jh];
            } else if (f < 272384u) {
                ((float*)(ws + OPB))[f - 264192u] = 0.f;
            } else {
                ((unsigned*)(ws + OCNT))[f - 272384u] = 0u;
            }
        }
    }
}

// A-frag pair load from [r][j] packed plane via agent-scope bypass loads
// (sees remote write-through stores without any L2-invalidating fence)
#define LDH(LO, HI, PL, RT, KB) do { \
    const unsigned long long* bp_ = (const unsigned long long*) \
        ((PL) + ((unsigned)(RT)*16u + (unsigned)n15)*256u \
              + (unsigned)(KB) + 4u*(unsigned)g4); \
    unsigned long long a_ = __hip_atomic_load(bp_,     __ATOMIC_RELAXED, __HIP_MEMORY_SCOPE_AGENT); \
    unsigned long long b_ = __hip_atomic_load(bp_ + 1, __ATOMIC_RELAXED, __HIP_MEMORY_SCOPE_AGENT); \
    unsigned long long c_ = __hip_atomic_load(bp_ + 8, __ATOMIC_RELAXED, __HIP_MEMORY_SCOPE_AGENT); \
    unsigned long long d_ = __hip_atomic_load(bp_ + 9, __ATOMIC_RELAXED, __HIP_MEMORY_SCOPE_AGENT); \
    (LO).x = (unsigned)a_; (LO).y = (unsigned)(a_ >> 32); \
    (LO).z = (unsigned)b_; (LO).w = (unsigned)(b_ >> 32); \
    (HI).x = (unsigned)c_; (HI).y = (unsigned)(c_ >> 32); \
    (HI).z = (unsigned)d_; (HI).w = (unsigned)(d_ >> 32); \
  } while (0)

#define UNPK(AH, AL, LO, HI) do { \
    AH[0]=(short)((LO).x>>16); AH[1]=(short)((LO).y>>16); \
    AH[2]=(short)((LO).z>>16); AH[3]=(short)((LO).w>>16); \
    AH[4]=(short)((HI).x>>16); AH[5]=(short)((HI).y>>16); \
    AH[6]=(short)((HI).z>>16); AH[7]=(short)((HI).w>>16); \
    AL[0]=(short)((LO).x&0xffffu); AL[1]=(short)((LO).y&0xffffu); \
    AL[2]=(short)((LO).z&0xffffu); AL[3]=(short)((LO).w&0xffffu); \
    AL[4]=(short)((HI).x&0xffffu); AL[5]=(short)((HI).y&0xffffu); \
    AL[6]=(short)((HI).z&0xffffu); AL[7]=(short)((HI).w&0xffffu); \
  } while (0)

#define MFMA4(ACC, AH, AL, BH, BL) do { \
    ACC = MFMA(AH, BH, ACC); ACC = MFMA(AL, BH, ACC); \
    ACC = MFMA(AH, BL, ACC); ACC = MFMA(AL, BL, ACC); \
  } while (0)

// 256 blocks x 256 threads (4 waves). Wave: jtl = wv>>1, rtl = wv&1 ->
// one jt, two rt, FULL K. Weights LDS-stationary (staged once).
// blocks [0,128): L1 step i-1 ; [128,256): L0 step i + FC step i-2
// (+ block 128: out for step i-3).
template<bool ISL1>
__device__ __forceinline__ void role(
    const float* __restrict__ x,
    const float* __restrict__ fc1b, const float* __restrict__ fc2w,
    const float* __restrict__ fc2b,
    char* __restrict__ ws, float* __restrict__ out,
    int blk, int wv, int lane, char* sm)
{
    const int tid  = wv*64 + lane;
    const int b    = blk & 127;
    const int jtl  = wv >> 1;
    const int rtl  = wv & 1;
    const int jbase = (b >> 2) * 2;
    const int jt   = jbase + jtl;
    const int rt0w = (b & 3)*4 + rtl*2;
    const int n15  = lane & 15, g4 = lane >> 4, q = lane & 3;
    const int jh   = jt*4 + (n15 >> 2);

    unsigned* const h0p   = (unsigned*)(ws + OH0P);
    unsigned* const h1p   = (unsigned*)(ws + OH1P);
    unsigned* const cnt   = (unsigned*)(ws + OCNT);
    unsigned* const epoch = (unsigned*)(ws + OCNT) + 16;   // separate line: read-only polls

    const int fjt = b >> 3, frt0 = (b & 7)*2;

    // ---- stage weights into LDS once ----
    if (ISL1) {
        for (int idx = tid; idx < 4096; idx += 256) {
            const int f = idx >> 6, inner = (idx & 63) << 4;
            const int jt2 = f >> 5, kt = (f >> 1) & 15, spl = f & 1;
            const char* src = ws + OW1F
                + ((size_t)((kt*64 + jbase + jt2)*2 + spl))*1024u + (unsigned)inner;
            *(uint4*)(sm + ((size_t)f << 10) + inner) = *(const uint4*)src;
        }
    } else {
        for (int idx = tid; idx < 3328; idx += 256) {
            const int f = idx >> 6, inner = (idx & 63) << 4;
            const char* src;
            if (f < 36) {
                const int jt2 = f / 18, r2 = f - jt2*18, kt = r2 >> 1, spl = r2 & 1;
                src = ws + OW0F
                    + ((size_t)((kt*64 + jbase + jt2)*2 + spl))*1024u + (unsigned)inner;
            } else {
                const int f2 = f - 36, kt = f2 >> 1, spl = f2 & 1;
                src = ws + OFCF
                    + ((size_t)((kt*16 + fjt)*2 + spl))*1024u + (unsigned)inner;
            }
            *(uint4*)(sm + ((size_t)f << 10) + inner) = *(const uint4*)src;
        }
    }
    const char* wlw = sm + ((size_t)jtl * (ISL1 ? 32u : 18u)) * 1024u;
    const char* fcw = sm + 36864u;                 // L0 only
    float* fcs = (float*)(sm + 53248u);            // L0 only, 8KB
    __syncthreads();

    const float4 bsv = *(const float4*)(ws + (ISL1 ? OB1S : OB0S) + (size_t)jh*16u);
    float c0[4] = {0,0,0,0}, c1[4] = {0,0,0,0};
    float fb1 = 0.f, fw2 = 0.f, f2b0 = 0.f;
    if (!ISL1) {
        fb1  = fc1b[fjt*16 + n15];
        fw2  = fc2w[fjt*16 + n15];
        f2b0 = fc2b[0];
    }

    #pragma unroll 1
    for (int i = 0; i < NITER; ++i) {
        const int s = ISL1 ? (i - 1) : i;
        const bool act = (s >= 0) && (s < TSTEPS);
        f4v acc0 = {0,0,0,0}, acc1 = {0,0,0,0};

        // FC h-loads issued early (hide under LSTM compute)
        const int sf = i - 2;
        const bool fact = (!ISL1) && (sf >= 0) && (sf < TSTEPS);
        uint4 fq[2][4];
        if (fact) {
            const unsigned* pf = h1p + (unsigned)(sf & 1) * 65536u;
            #pragma unroll
            for (int kl = 0; kl < 2; ++kl) {
                const int ktf = 2*wv + kl;
                LDH(fq[kl][0], fq[kl][1], pf, frt0,     ktf*32);
                LDH(fq[kl][2], fq[kl][3], pf, frt0 + 1, ktf*32);
            }
        }

        if (act) {
            uint4 hq[4][4];
            if (ISL1) {
                const unsigned* P0 = h0p + (unsigned)(s & 1) * 65536u;        // h0(s)
                const unsigned* P1 = h1p + (unsigned)((s + 1) & 1) * 65536u;  // h1(s-1)
                #pragma unroll
                for (int t = 0; t < 4; ++t) {
                    LDH(hq[t][0], hq[t][1], P0, rt0w,     t*32);
                    LDH(hq[t][2], hq[t][3], P0, rt0w + 1, t*32);
                }
                #pragma unroll
                for (int t = 0; t < 16; ++t) {
                    const int sl = t & 3;
                    s8v bh = *(const s8v*)(wlw + ((size_t)(t*2)    << 10) + (size_t)lane*16u);
                    s8v bl = *(const s8v*)(wlw + ((size_t)(t*2 + 1) << 10) + (size_t)lane*16u);
                    s8v ah, al;
                    UNPK(ah, al, hq[sl][0], hq[sl][1]);
                    MFMA4(acc0, ah, al, bh, bl);
                    UNPK(ah, al, hq[sl][2], hq[sl][3]);
                    MFMA4(acc1, ah, al, bh, bl);
                    if (t + 4 < 16) {
                        const int kn = t + 4;
                        const unsigned* Pn = (kn < 8) ? P0 : P1;
                        const int cb = (kn & 7) * 32;
                        LDH(hq[sl][0], hq[sl][1], Pn, rt0w,     cb);
                        LDH(hq[sl][2], hq[sl][3], Pn, rt0w + 1, cb);
                    }
                }
            } else {
                const unsigned* P0 = h0p + (unsigned)((s + 1) & 1) * 65536u;  // h0(s-1)
                #pragma unroll
                for (int t = 0; t < 4; ++t) {
                    LDH(hq[t][0], hq[t][1], P0, rt0w,     t*32);
                    LDH(hq[t][2], hq[t][3], P0, rt0w + 1, t*32);
                }
                {   // x-projection: B tile 0 = [x(16) | zero-pad]
                    s8v bh = *(const s8v*)(wlw + (size_t)lane*16u);
                    s8v bl = *(const s8v*)(wlw + 1024u + (size_t)lane*16u);
                    #pragma unroll
                    for (int d = 0; d < 2; ++d) {
                        const int r = (rt0w + d)*16 + n15;
                        const float4 xv = *(const float4*)(x + ((size_t)r*TSTEPS + s)*16u
                                                             + 4u*(unsigned)g4);
                        float xs[4] = {xv.x, xv.y, xv.z, xv.w};
                        s8v ah, al;
                        #pragma unroll
                        for (int e = 0; e < 4; ++e) {
                            short hv2 = bf_hi(xs[e]);
                            ah[e] = hv2; al[e] = bf_hi(xs[e] - bf_f(hv2));
                            ah[e + 4] = 0; al[e + 4] = 0;
                        }
                        if (d == 0) MFMA4(acc0, ah, al, bh, bl);
                        else        MFMA4(acc1, ah, al, bh, bl);
                    }
                }
                #pragma unroll
                for (int t = 0; t < 8; ++t) {
                    const int sl = t & 3;
                    s8v bh = *(const s8v*)(wlw + ((size_t)((t+1)*2)     << 10) + (size_t)lane*16u);
                    s8v bl = *(const s8v*)(wlw + ((size_t)((t+1)*2 + 1) << 10) + (size_t)lane*16u);
                    s8v ah, al;
                    UNPK(ah, al, hq[sl][0], hq[sl][1]);
                    MFMA4(acc0, ah, al, bh, bl);
                    UNPK(ah, al, hq[sl][2], hq[sl][3]);
                    MFMA4(acc1, ah, al, bh, bl);
                    if (t + 4 < 8) {
                        const int cb = (t + 4) * 32;
                        LDH(hq[sl][0], hq[sl][1], P0, rt0w,     cb);
                        LDH(hq[sl][2], hq[sl][3], P0, rt0w + 1, cb);
                    }
                }
            }

            // ---- cell update (gate quads), store packed h [r][j] ----
            unsigned* hwp = (ISL1 ? h1p : h0p) + (unsigned)(s & 1) * 65536u;
            #pragma unroll
            for (int d = 0; d < 2; ++d) {
                const int rt = rt0w + d;
                f4v av = d ? acc1 : acc0;
                float* cc = d ? c1 : c0;
                unsigned pk[4];
                #pragma unroll
                for (int e = 0; e < 4; ++e) {
                    float v0 = av[e];
                    float v1 = __shfl_xor(v0, 1);
                    float v2 = __shfl_xor(v0, 2);
                    float v3 = __shfl_xor(v1, 2);
                    float gi = (q==0)? v0 : (q==1)? v1 : (q==2)? v2 : v3;
                    float gf = (q==0)? v1 : (q==1)? v0 : (q==2)? v3 : v2;
                    float gg = (q==0)? v2 : (q==1)? v3 : (q==2)? v0 : v1;
                    float go = (q==0)? v3 : (q==1)? v2 : (q==2)? v1 : v0;
                    float ig = fast_sigmoid(gi + bsv.x);
                    float fg = fast_sigmoid(gf + bsv.y);
                    float gt = fast_tanh   (gg + bsv.z);
                    float og = fast_sigmoid(go + bsv.w);
                    float cn = fg * cc[e] + ig * gt;
                    cc[e] = cn;
                    float h = og * fast_tanh(cn);
                    short hv = bf_hi(h);
                    short lv = bf_hi(h - bf_f(hv));
                    pk[e] = ((unsigned)(unsigned short)hv << 16) | (unsigned)(unsigned short)lv;
                }
                if (q == 0) {
                    #pragma unroll
                    for (int e = 0; e < 4; ++e) {
                        const int r = rt*16 + 4*g4 + e;
                        __hip_atomic_store(hwp + (unsigned)r*256u + (unsigned)jh, pk[e],
                                           __ATOMIC_RELAXED, __HIP_MEMORY_SCOPE_AGENT);
                    }
                }
            }
        }

        if (!ISL1) {
            // ---- FC: fc1 + relu + fc2 partials for step i-2 ----
            if (fact) {
                f4v fa0 = {0,0,0,0}, fa1 = {0,0,0,0};
                #pragma unroll
                for (int kl = 0; kl < 2; ++kl) {
                    const int ktf = 2*wv + kl;
                    s8v fh = *(const s8v*)(fcw + ((size_t)(ktf*2)     << 10) + (size_t)lane*16u);
                    s8v fl = *(const s8v*)(fcw + ((size_t)(ktf*2 + 1) << 10) + (size_t)lane*16u);
                    s8v ah, al;
                    UNPK(ah, al, fq[kl][0], fq[kl][1]);
                    MFMA4(fa0, ah, al, fh, fl);
                    UNPK(ah, al, fq[kl][2], fq[kl][3]);
                    MFMA4(fa1, ah, al, fh, fl);
                }
                *(f4v*)&fcs[(wv*2 + 0)*256 + lane*4] = fa0;
                *(f4v*)&fcs[(wv*2 + 1)*256 + lane*4] = fa1;
            }
            __syncthreads();
            if (fact && wv == 0) {
                #pragma unroll
                for (int d = 0; d < 2; ++d) {
                    f4v av = {0,0,0,0};
                    #pragma unroll
                    for (int w2 = 0; w2 < 4; ++w2)
                        av = av + *(const f4v*)&fcs[(w2*2 + d)*256 + lane*4];
                    float pe[4];
                    #pragma unroll
                    for (int e = 0; e < 4; ++e) {
                        float v = av[e] + fb1;
                        v = v > 0.f ? v : 0.f;
                        float p = v * fw2;
                        p += __shfl_xor(p, 1);
                        p += __shfl_xor(p, 2);
                        p += __shfl_xor(p, 4);
                        p += __shfl_xor(p, 8);
                        pe[e] = p;
                    }
                    if (n15 == 0) {
                        unsigned* pb = (unsigned*)(ws + OPB) + (unsigned)(i & 1)*4096u
                                       + (unsigned)(fjt*256 + (frt0 + d)*16 + 4*g4);
                        unsigned long long lo =
                            ((unsigned long long)__builtin_bit_cast(unsigned, pe[1]) << 32)
                            | __builtin_bit_cast(unsigned, pe[0]);
                        unsigned long long hi =
                            ((unsigned long long)__builtin_bit_cast(unsigned, pe[3]) << 32)
                            | __builtin_bit_cast(unsigned, pe[2]);
                        __hip_atomic_store((unsigned long long*)pb,       lo, __ATOMIC_RELAXED, __HIP_MEMORY_SCOPE_AGENT);
                        __hip_atomic_store((unsigned long long*)(pb + 2), hi, __ATOMIC_RELAXED, __HIP_MEMORY_SCOPE_AGENT);
                    }
                }
            }
            // ---- out: final fc2 reduce for step i-3 (block 128 only) ----
            if (b == 0 && i >= 3) {
                const int tt = i - 3;
                const unsigned* pb2 = (const unsigned*)(ws + OPB)
                                      + (unsigned)((i - 1) & 1)*4096u;
                float ssum = f2b0;
                #pragma unroll
                for (int jx = 0; jx < 16; ++jx) {
                    unsigned uv = __hip_atomic_load(pb2 + jx*256 + tid,
                                                    __ATOMIC_RELAXED, __HIP_MEMORY_SCOPE_AGENT);
                    ssum += __builtin_bit_cast(float, uv);
                }
                __hip_atomic_store((unsigned*)&out[(size_t)tid*TSTEPS + tt],
                                   __builtin_bit_cast(unsigned, ssum),
                                   __ATOMIC_RELAXED, __HIP_MEMORY_SCOPE_AGENT);
            }
        }

        // ---- decontended grid barrier: arrivals on cnt, broadcast via epoch ----
        __syncthreads();   // drains vmcnt -> all write-through stores ACKed
        if (tid == 0) {
            const unsigned tgt = 256u * (unsigned)(i + 1);
            unsigned old = __hip_atomic_fetch_add(cnt, 1u, __ATOMIC_RELAXED,
                                                  __HIP_MEMORY_SCOPE_AGENT);
            if (old == tgt - 1u) {
                __hip_atomic_store(epoch, tgt, __ATOMIC_RELAXED, __HIP_MEMORY_SCOPE_AGENT);
            } else {
                while (__hip_atomic_load(epoch, __ATOMIC_RELAXED,
                                         __HIP_MEMORY_SCOPE_AGENT) < tgt)
                    __builtin_amdgcn_s_sleep(4);
            }
        }
        __syncthreads();
    }
}

__global__ __launch_bounds__(256, 1) void lstm_mfma(
    const float* __restrict__ x, const float* __restrict__ fc1b,
    const float* __restrict__ fc2w, const float* __restrict__ fc2b,
    char* __restrict__ ws, float* __restrict__ out)
{
    __shared__ __align__(16) char sm[65536];
    const int tid  = threadIdx.x;
    const int lane = tid & 63;
    const int wv   = __builtin_amdgcn_readfirstlane(tid >> 6);
    const int blk  = blockIdx.x;
    if (blk < 128) role<true >(x, fc1b, fc2w, fc2b, ws, out, blk, wv, lane, sm);
    else           role<false>(x, fc1b, fc2w, fc2b, ws, out, blk, wv, lane, sm);
}

extern "C" void kernel_launch(void* const* d_in, const int* in_sizes, int n_in,
                              void* d_out, int out_size, void* d_ws, size_t ws_size,
                              hipStream_t stream)
{
    const float* x    = (const float*)d_in[0];
    const float* Wih0 = (const float*)d_in[1];
    const float* Whh0 = (const float*)d_in[2];
    const float* bih0 = (const float*)d_in[3];
    const float* bhh0 = (const float*)d_in[4];
    const float* Wih1 = (const float*)d_in[5];
    const float* Whh1 = (const float*)d_in[6];
    const float* bih1 = (const float*)d_in[7];
    const float* bhh1 = (const float*)d_in[8];
    const float* fc1w = (const float*)d_in[9];
    const float* fc1b = (const float*)d_in[10];
    const float* fc2w = (const float*)d_in[11];
    const float* fc2b = (const float*)d_in[12];
    char*  ws  = (char*)d_ws;
    float* out = (float*)d_out;

    prep_kernel<<<1024, 256, 0, stream>>>(Wih0, Whh0, bih0, bhh0,
                                          Wih1, Whh1, bih1, bhh1, fc1w, ws);

    void* args[] = {(void*)&x, (void*)&fc1b, (void*)&fc2w, (void*)&fc2b,
                    (void*)&ws, (void*)&out};
    hipLaunchCooperativeKernel((const void*)lstm_mfma, dim3(256), dim3(256),
                               args, 0, stream);
}

// Round 14
// 17031.097 us; speedup vs baseline: 1.8583x; 1.1952x over previous
//
#include <hip/hip_runtime.h>
#include <math.h>

#define TSTEPS 1024
#define NITER  1027

typedef __attribute__((ext_vector_type(8))) short s8v;   // bf16x8 MFMA frag
typedef __attribute__((ext_vector_type(4))) float f4v;   // f32x4 acc

// ---- ws byte offsets ----
// W1F [16kt][64jt][2spl] 1KB frags ; W0F [9][64][2] ; FCF [8][16][2]
// H0P/H1P [2 parity][256 r][256 j] u32 = (bf16hi<<16)|bf16lo
// B0S/B1S [256 jh][4 gate] f32 ; PB [2][16][256] f32
// CNT: cnt[pair] at +pair*256B ; (epoch at +2KB+pair*256B)
#define OW1F 0u
#define OW0F 2097152u
#define OFCF 3276800u
#define OH0P 3538944u
#define OH1P 4063232u
#define OB0S 4587520u
#define OB1S 4591616u
#define OPB  4595712u
#define OCNT 4628480u

#define MFMA(A,B,C) __builtin_amdgcn_mfma_f32_16x16x32_bf16(A, B, C, 0, 0, 0)

__device__ __forceinline__ short bf_hi(float v) {
    unsigned u = __builtin_bit_cast(unsigned, v);
    unsigned r = (u + 0x7FFFu + ((u >> 16) & 1u)) >> 16;
    return (short)r;
}
__device__ __forceinline__ float bf_f(short h) {
    unsigned u = ((unsigned)(unsigned short)h) << 16;
    return __builtin_bit_cast(float, u);
}
__device__ __forceinline__ float fast_sigmoid(float v) {
    return __builtin_amdgcn_rcpf(1.0f + __expf(-v));
}
__device__ __forceinline__ float fast_tanh(float v) {
    return 1.0f - 2.0f * __builtin_amdgcn_rcpf(1.0f + __expf(2.0f * v));
}

// ---- prep: identical to R9-R13 (validated) ----
#define NSH_W1 1048576u
#define NSH_W0 589824u
#define NSH_TOT 1769472u
#define NTAIL 273408u

__global__ __launch_bounds__(256) void prep_kernel(
    const float* __restrict__ Wih0, const float* __restrict__ Whh0,
    const float* __restrict__ bih0, const float* __restrict__ bhh0,
    const float* __restrict__ Wih1, const float* __restrict__ Whh1,
    const float* __restrict__ bih1, const float* __restrict__ bhh1,
    const float* __restrict__ fc1w,
    char* __restrict__ ws)
{
    const unsigned NTOT = NSH_TOT + NTAIL;
    for (unsigned idx = blockIdx.x * blockDim.x + threadIdx.x; idx < NTOT;
         idx += gridDim.x * blockDim.x) {
        if (idx < NSH_TOT) {
            unsigned i2, mode, off;
            if (idx < NSH_W1)               { i2 = idx;                  mode = 0; off = OW1F; }
            else if (idx < NSH_W1 + NSH_W0) { i2 = idx - NSH_W1;         mode = 1; off = OW0F; }
            else                            { i2 = idx - NSH_W1 - NSH_W0; mode = 2; off = OFCF; }
            unsigned frag = i2 >> 9, el = i2 & 511u;
            unsigned lane = el >> 3, e = el & 7u;
            unsigned spl = frag & 1u, jtw = frag >> 1;
            unsigned n = lane & 15u, g = lane >> 4;
            unsigned kw = 4u*g + (e & 3u) + ((e >> 2) << 4);
            float w = 0.f;
            if (mode == 2) {
                unsigned jt = jtw & 15u, kt = frag >> 5;
                unsigned row = jt*16u + n;
                w = fc1w[row*256u + kt*32u + kw];
            } else {
                unsigned jt = jtw & 63u, kt = frag >> 7;
                unsigned row = (n & 3u)*256u + jt*4u + (n >> 2);
                unsigned kg = kt*32u + kw;
                if (mode == 0) {
                    w = (kg < 256u) ? Wih1[row*256u + kg] : Whh1[row*256u + (kg - 256u)];
                } else {
                    if (kt == 0u) w = (kw < 16u) ? Wih0[row*16u + kw] : 0.f;
                    else          w = Whh0[row*256u + (kg - 32u)];
                }
            }
            short hv = bf_hi(w);
            short val = spl ? bf_hi(w - bf_f(hv)) : hv;
            *(short*)(ws + off + (size_t)frag*1024u + (size_t)el*2u) = val;
        } else {
            unsigned f = idx - NSH_TOT;
            if (f < 262144u) {
                ((unsigned*)(ws + OH0P))[f] = 0u;
            } else if (f < 263168u) {
                unsigned i3 = f - 262144u, jh = i3 >> 2, gq = i3 & 3u;
                ((float*)(ws + OB0S))[i3] = bih0[gq*256u + jh] + bhh0[gq*256u + jh];
            } else if (f < 264192u) {
                unsigned i3 = f - 263168u, jh = i3 >> 2, gq = i3 & 3u;
                ((float*)(ws + OB1S))[i3] = bih1[gq*256u + jh] + bhh1[gq*256u + jh];
            } else if (f < 272384u) {
                ((float*)(ws + OPB))[f - 264192u] = 0.f;
            } else {
                ((unsigned*)(ws + OCNT))[f - 272384u] = 0u;
            }
        }
    }
}

// A-frag pair load from [r][j] packed plane: PLAIN cached loads (L2 serves the
// intra-pair reuse; cross-iteration coherence via per-iter acquire fence)
#define LDH(LO, HI, PL, RT, KB) do { \
    const unsigned* bp_ = (PL) + ((unsigned)(RT)*16u + (unsigned)n15)*256u \
                               + (unsigned)(KB) + 4u*(unsigned)g4; \
    LO = *(const uint4*)bp_; HI = *(const uint4*)(bp_ + 16); \
  } while (0)

#define UNPK(AH, AL, LO, HI) do { \
    AH[0]=(short)((LO).x>>16); AH[1]=(short)((LO).y>>16); \
    AH[2]=(short)((LO).z>>16); AH[3]=(short)((LO).w>>16); \
    AH[4]=(short)((HI).x>>16); AH[5]=(short)((HI).y>>16); \
    AH[6]=(short)((HI).z>>16); AH[7]=(short)((HI).w>>16); \
    AL[0]=(short)((LO).x&0xffffu); AL[1]=(short)((LO).y&0xffffu); \
    AL[2]=(short)((LO).z&0xffffu); AL[3]=(short)((LO).w&0xffffu); \
    AL[4]=(short)((HI).x&0xffffu); AL[5]=(short)((HI).y&0xffffu); \
    AL[6]=(short)((HI).z&0xffffu); AL[7]=(short)((HI).w&0xffffu); \
  } while (0)

#define MFMA4(ACC, AH, AL, BH, BL) do { \
    ACC = MFMA(AH, BH, ACC); ACC = MFMA(AL, BH, ACC); \
    ACC = MFMA(AH, BL, ACC); ACC = MFMA(AL, BL, ACC); \
  } while (0)

// 256 blocks x 256 threads. XCD-aligned partition (xcd = blk&7, pair g = xcd>>1):
//   XCD pair g owns batch rows [64g, 64g+64) for ALL roles.
//   Per XCD: slots 0..15 -> L1 (u = side*16+slot), 16..31 -> L0 (+FC).
//   ALL data edges (incl. out) are pair-local -> 4 fully independent pair groups,
//   each with its own 64-arrival barrier. Pair's out-writer = slot16/side0 block,
//   reduces the pair's own 64 rows from PB (2-parity safe: intra-pair drift <= 1).
template<bool ISL1>
__device__ __forceinline__ void role(
    const float* __restrict__ x,
    const float* __restrict__ fc1b, const float* __restrict__ fc2w,
    const float* __restrict__ fc2b,
    char* __restrict__ ws, float* __restrict__ out,
    int g, int u, bool isOut, int wv, int lane, char* sm)
{
    const int tid  = wv*64 + lane;
    const int jtl  = wv >> 1;
    const int rtl  = wv & 1;
    const int jbase = u * 2;
    const int jt   = jbase + jtl;
    const int rt0w = g*4 + rtl*2;
    const int n15  = lane & 15, g4 = lane >> 4, q = lane & 3;
    const int jh   = jt*4 + (n15 >> 2);

    unsigned* const h0p = (unsigned*)(ws + OH0P);
    unsigned* const h1p = (unsigned*)(ws + OH1P);
    unsigned* const cnt = (unsigned*)(ws + OCNT);
    unsigned* const eps = (unsigned*)(ws + OCNT) + 512;
    unsigned* const mycnt = cnt + g*64;
    unsigned* const myep  = eps + g*64;

    const int fjt = u & 15, frt0 = g*4 + (u >> 4)*2;

    // ---- stage weights into LDS once ----
    if (ISL1) {
        for (int idx = tid; idx < 4096; idx += 256) {
            const int f = idx >> 6, inner = (idx & 63) << 4;
            const int jt2 = f >> 5, kt = (f >> 1) & 15, spl = f & 1;
            const char* src = ws + OW1F
                + ((size_t)((kt*64 + jbase + jt2)*2 + spl))*1024u + (unsigned)inner;
            *(uint4*)(sm + ((size_t)f << 10) + inner) = *(const uint4*)src;
        }
    } else {
        for (int idx = tid; idx < 3328; idx += 256) {
            const int f = idx >> 6, inner = (idx & 63) << 4;
            const char* src;
            if (f < 36) {
                const int jt2 = f / 18, r2 = f - jt2*18, kt = r2 >> 1, spl = r2 & 1;
                src = ws + OW0F
                    + ((size_t)((kt*64 + jbase + jt2)*2 + spl))*1024u + (unsigned)inner;
            } else {
                const int f2 = f - 36, kt = f2 >> 1, spl = f2 & 1;
                src = ws + OFCF
                    + ((size_t)((kt*16 + fjt)*2 + spl))*1024u + (unsigned)inner;
            }
            *(uint4*)(sm + ((size_t)f << 10) + inner) = *(const uint4*)src;
        }
    }
    const char* wlw = sm + ((size_t)jtl * (ISL1 ? 32u : 18u)) * 1024u;
    const char* fcw = sm + 36864u;                 // L0 only
    float* fcs = (float*)(sm + 53248u);            // L0 only, 8KB
    __syncthreads();

    const float4 bsv = *(const float4*)(ws + (ISL1 ? OB1S : OB0S) + (size_t)jh*16u);
    float c0[4] = {0,0,0,0}, c1[4] = {0,0,0,0};
    float fb1 = 0.f, fw2 = 0.f, f2b0 = 0.f;
    if (!ISL1) {
        fb1  = fc1b[fjt*16 + n15];
        fw2  = fc2w[fjt*16 + n15];
        f2b0 = fc2b[0];
    }

    #pragma unroll 1
    for (int i = 0; i < NITER; ++i) {
        const int s = ISL1 ? (i - 1) : i;
        const bool act = (s >= 0) && (s < TSTEPS);
        f4v acc0 = {0,0,0,0}, acc1 = {0,0,0,0};

        // FC h-loads issued early (hide under LSTM compute)
        const int sf = i - 2;
        const bool fact = (!ISL1) && (sf >= 0) && (sf < TSTEPS);
        uint4 fq[2][4];
        if (fact) {
            const unsigned* pf = h1p + (unsigned)(sf & 1) * 65536u;
            #pragma unroll
            for (int kl = 0; kl < 2; ++kl) {
                const int ktf = 2*wv + kl;
                LDH(fq[kl][0], fq[kl][1], pf, frt0,     ktf*32);
                LDH(fq[kl][2], fq[kl][3], pf, frt0 + 1, ktf*32);
            }
        }

        if (act) {
            uint4 hq[4][4];
            if (ISL1) {
                const unsigned* P0 = h0p + (unsigned)(s & 1) * 65536u;        // h0(s)
                const unsigned* P1 = h1p + (unsigned)((s + 1) & 1) * 65536u;  // h1(s-1)
                #pragma unroll
                for (int t = 0; t < 4; ++t) {
                    LDH(hq[t][0], hq[t][1], P0, rt0w,     t*32);
                    LDH(hq[t][2], hq[t][3], P0, rt0w + 1, t*32);
                }
                #pragma unroll
                for (int t = 0; t < 16; ++t) {
                    const int sl = t & 3;
                    s8v bh = *(const s8v*)(wlw + ((size_t)(t*2)    << 10) + (size_t)lane*16u);
                    s8v bl = *(const s8v*)(wlw + ((size_t)(t*2 + 1) << 10) + (size_t)lane*16u);
                    s8v ah, al;
                    UNPK(ah, al, hq[sl][0], hq[sl][1]);
                    MFMA4(acc0, ah, al, bh, bl);
                    UNPK(ah, al, hq[sl][2], hq[sl][3]);
                    MFMA4(acc1, ah, al, bh, bl);
                    if (t + 4 < 16) {
                        const int kn = t + 4;
                        const unsigned* Pn = (kn < 8) ? P0 : P1;
                        const int cb = (kn & 7) * 32;
                        LDH(hq[sl][0], hq[sl][1], Pn, rt0w,     cb);
                        LDH(hq[sl][2], hq[sl][3], Pn, rt0w + 1, cb);
                    }
                }
            } else {
                const unsigned* P0 = h0p + (unsigned)((s + 1) & 1) * 65536u;  // h0(s-1)
                #pragma unroll
                for (int t = 0; t < 4; ++t) {
                    LDH(hq[t][0], hq[t][1], P0, rt0w,     t*32);
                    LDH(hq[t][2], hq[t][3], P0, rt0w + 1, t*32);
                }
                {   // x-projection: B tile 0 = [x(16) | zero-pad]
                    s8v bh = *(const s8v*)(wlw + (size_t)lane*16u);
                    s8v bl = *(const s8v*)(wlw + 1024u + (size_t)lane*16u);
                    #pragma unroll
                    for (int d = 0; d < 2; ++d) {
                        const int r = (rt0w + d)*16 + n15;
                        const float4 xv = *(const float4*)(x + ((size_t)r*TSTEPS + s)*16u
                                                             + 4u*(unsigned)g4);
                        float xs[4] = {xv.x, xv.y, xv.z, xv.w};
                        s8v ah, al;
                        #pragma unroll
                        for (int e = 0; e < 4; ++e) {
                            short hv2 = bf_hi(xs[e]);
                            ah[e] = hv2; al[e] = bf_hi(xs[e] - bf_f(hv2));
                            ah[e + 4] = 0; al[e + 4] = 0;
                        }
                        if (d == 0) MFMA4(acc0, ah, al, bh, bl);
                        else        MFMA4(acc1, ah, al, bh, bl);
                    }
                }
                #pragma unroll
                for (int t = 0; t < 8; ++t) {
                    const int sl = t & 3;
                    s8v bh = *(const s8v*)(wlw + ((size_t)((t+1)*2)     << 10) + (size_t)lane*16u);
                    s8v bl = *(const s8v*)(wlw + ((size_t)((t+1)*2 + 1) << 10) + (size_t)lane*16u);
                    s8v ah, al;
                    UNPK(ah, al, hq[sl][0], hq[sl][1]);
                    MFMA4(acc0, ah, al, bh, bl);
                    UNPK(ah, al, hq[sl][2], hq[sl][3]);
                    MFMA4(acc1, ah, al, bh, bl);
                    if (t + 4 < 8) {
                        const int cb = (t + 4) * 32;
                        LDH(hq[sl][0], hq[sl][1], P0, rt0w,     cb);
                        LDH(hq[sl][2], hq[sl][3], P0, rt0w + 1, cb);
                    }
                }
            }

            // ---- cell update (gate quads), store packed h [r][j] write-through ----
            unsigned* hwp = (ISL1 ? h1p : h0p) + (unsigned)(s & 1) * 65536u;
            #pragma unroll
            for (int d = 0; d < 2; ++d) {
                const int rt = rt0w + d;
                f4v av = d ? acc1 : acc0;
                float* cc = d ? c1 : c0;
                unsigned pk[4];
                #pragma unroll
                for (int e = 0; e < 4; ++e) {
                    float v0 = av[e];
                    float v1 = __shfl_xor(v0, 1);
                    float v2 = __shfl_xor(v0, 2);
                    float v3 = __shfl_xor(v1, 2);
                    float gi = (q==0)? v0 : (q==1)? v1 : (q==2)? v2 : v3;
                    float gf = (q==0)? v1 : (q==1)? v0 : (q==2)? v3 : v2;
                    float gg = (q==0)? v2 : (q==1)? v3 : (q==2)? v0 : v1;
                    float go = (q==0)? v3 : (q==1)? v2 : (q==2)? v1 : v0;
                    float ig = fast_sigmoid(gi + bsv.x);
                    float fg = fast_sigmoid(gf + bsv.y);
                    float gt = fast_tanh   (gg + bsv.z);
                    float og = fast_sigmoid(go + bsv.w);
                    float cn = fg * cc[e] + ig * gt;
                    cc[e] = cn;
                    float h = og * fast_tanh(cn);
                    short hv = bf_hi(h);
                    short lv = bf_hi(h - bf_f(hv));
                    pk[e] = ((unsigned)(unsigned short)hv << 16) | (unsigned)(unsigned short)lv;
                }
                if (q == 0) {
                    #pragma unroll
                    for (int e = 0; e < 4; ++e) {
                        const int r = rt*16 + 4*g4 + e;
                        __hip_atomic_store(hwp + (unsigned)r*256u + (unsigned)jh, pk[e],
                                           __ATOMIC_RELAXED, __HIP_MEMORY_SCOPE_AGENT);
                    }
                }
            }
        }

        if (!ISL1) {
            // ---- FC: fc1 + relu + fc2 partials for step i-2 ----
            if (fact) {
                f4v fa0 = {0,0,0,0}, fa1 = {0,0,0,0};
                #pragma unroll
                for (int kl = 0; kl < 2; ++kl) {
                    const int ktf = 2*wv + kl;
                    s8v fh = *(const s8v*)(fcw + ((size_t)(ktf*2)     << 10) + (size_t)lane*16u);
                    s8v fl = *(const s8v*)(fcw + ((size_t)(ktf*2 + 1) << 10) + (size_t)lane*16u);
                    s8v ah, al;
                    UNPK(ah, al, fq[kl][0], fq[kl][1]);
                    MFMA4(fa0, ah, al, fh, fl);
                    UNPK(ah, al, fq[kl][2], fq[kl][3]);
                    MFMA4(fa1, ah, al, fh, fl);
                }
                *(f4v*)&fcs[(wv*2 + 0)*256 + lane*4] = fa0;
                *(f4v*)&fcs[(wv*2 + 1)*256 + lane*4] = fa1;
            }
            __syncthreads();
            if (fact && wv == 0) {
                #pragma unroll
                for (int d = 0; d < 2; ++d) {
                    f4v av = {0,0,0,0};
                    #pragma unroll
                    for (int w2 = 0; w2 < 4; ++w2)
                        av = av + *(const f4v*)&fcs[(w2*2 + d)*256 + lane*4];
                    float pe[4];
                    #pragma unroll
                    for (int e = 0; e < 4; ++e) {
                        float v = av[e] + fb1;
                        v = v > 0.f ? v : 0.f;
                        float p = v * fw2;
                        p += __shfl_xor(p, 1);
                        p += __shfl_xor(p, 2);
                        p += __shfl_xor(p, 4);
                        p += __shfl_xor(p, 8);
                        pe[e] = p;
                    }
                    if (n15 == 0) {
                        unsigned* pb = (unsigned*)(ws + OPB) + (unsigned)(i & 1)*4096u
                                       + (unsigned)(fjt*256 + (frt0 + d)*16 + 4*g4);
                        unsigned long long lo =
                            ((unsigned long long)__builtin_bit_cast(unsigned, pe[1]) << 32)
                            | __builtin_bit_cast(unsigned, pe[0]);
                        unsigned long long hi =
                            ((unsigned long long)__builtin_bit_cast(unsigned, pe[3]) << 32)
                            | __builtin_bit_cast(unsigned, pe[2]);
                        __hip_atomic_store((unsigned long long*)pb,       lo, __ATOMIC_RELAXED, __HIP_MEMORY_SCOPE_AGENT);
                        __hip_atomic_store((unsigned long long*)(pb + 2), hi, __ATOMIC_RELAXED, __HIP_MEMORY_SCOPE_AGENT);
                    }
                }
            }
            // ---- out: per-pair final fc2 reduce for step i-3 (pair-local rows) ----
            if (isOut && i >= 3 && tid < 64) {
                const int tt = i - 3;
                const int r = g*64 + tid;
                const unsigned* pb2 = (const unsigned*)(ws + OPB)
                                      + (unsigned)((i - 1) & 1)*4096u;
                float ssum = f2b0;
                #pragma unroll
                for (int jx = 0; jx < 16; ++jx) {
                    unsigned uv = __hip_atomic_load(pb2 + jx*256 + r,
                                                    __ATOMIC_RELAXED, __HIP_MEMORY_SCOPE_AGENT);
                    ssum += __builtin_bit_cast(float, uv);
                }
                __hip_atomic_store((unsigned*)&out[(size_t)r*TSTEPS + tt],
                                   __builtin_bit_cast(unsigned, ssum),
                                   __ATOMIC_RELAXED, __HIP_MEMORY_SCOPE_AGENT);
            }
        }

        // ---- per-pair barrier (64 arrivals) + acquire fence (L2 invalidate) ----
        __syncthreads();   // drains vmcnt -> all write-through stores ACKed
        if (tid == 0) {
            const unsigned tgt = 64u * (unsigned)(i + 1);
            unsigned old = __hip_atomic_fetch_add(mycnt, 1u, __ATOMIC_RELAXED,
                                                  __HIP_MEMORY_SCOPE_AGENT);
            if (old == tgt - 1u) {
                __hip_atomic_store(myep, (unsigned)(i + 1), __ATOMIC_RELAXED,
                                   __HIP_MEMORY_SCOPE_AGENT);
            } else {
                while (__hip_atomic_load(myep, __ATOMIC_RELAXED,
                                         __HIP_MEMORY_SCOPE_AGENT) < (unsigned)(i + 1))
                    __builtin_amdgcn_s_sleep(2);
            }
        }
        __syncthreads();
        __builtin_amdgcn_fence(__ATOMIC_ACQUIRE, "agent");   // invalidate (no writeback)
    }
}

__global__ __launch_bounds__(256, 1) void lstm_mfma(
    const float* __restrict__ x, const float* __restrict__ fc1b,
    const float* __restrict__ fc2w, const float* __restrict__ fc2b,
    char* __restrict__ ws, float* __restrict__ out)
{
    __shared__ __align__(16) char sm[65536];
    const int tid  = threadIdx.x;
    const int lane = tid & 63;
    const int wv   = __builtin_amdgcn_readfirstlane(tid >> 6);
    const int blk  = blockIdx.x;
    const int xcd  = blk & 7, slot = blk >> 3;
    const int g    = xcd >> 1, side = xcd & 1;
    if (slot < 16)
        role<true >(x, fc1b, fc2w, fc2b, ws, out, g, side*16 + slot, false,
                    wv, lane, sm);
    else
        role<false>(x, fc1b, fc2w, fc2b, ws, out, g, side*16 + (slot - 16),
                    (slot == 16) && (side == 0), wv, lane, sm);
}

extern "C" void kernel_launch(void* const* d_in, const int* in_sizes, int n_in,
                              void* d_out, int out_size, void* d_ws, size_t ws_size,
                              hipStream_t stream)
{
    const float* x    = (const float*)d_in[0];
    const float* Wih0 = (const float*)d_in[1];
    const float* Whh0 = (const float*)d_in[2];
    const float* bih0 = (const float*)d_in[3];
    const float* bhh0 = (const float*)d_in[4];
    const float* Wih1 = (const float*)d_in[5];
    const float* Whh1 = (const float*)d_in[6];
    const float* bih1 = (const float*)d_in[7];
    const float* bhh1 = (const float*)d_in[8];
    const float* fc1w = (const float*)d_in[9];
    const float* fc1b = (const float*)d_in[10];
    const float* fc2w = (const float*)d_in[11];
    const float* fc2b = (const float*)d_in[12];
    char*  ws  = (char*)d_ws;
    float* out = (float*)d_out;

    prep_kernel<<<1024, 256, 0, stream>>>(Wih0, Whh0, bih0, bhh0,
                                          Wih1, Whh1, bih1, bhh1, fc1w, ws);

    void* args[] = {(void*)&x, (void*)&fc1b, (void*)&fc2w, (void*)&fc2b,
                    (void*)&ws, (void*)&out};
    hipLaunchCooperativeKernel((const void*)lstm_mfma, dim3(256), dim3(256),
                               args, 0, stream);
}

// Round 15
// 16809.818 us; speedup vs baseline: 1.8827x; 1.0132x over previous
//
#include <hip/hip_runtime.h>
#include <math.h>

#define TSTEPS 1024
#define NITER  1027

typedef __attribute__((ext_vector_type(8))) short s8v;   // bf16x8 MFMA frag
typedef __attribute__((ext_vector_type(4))) float f4v;   // f32x4 acc

// ---- ws byte offsets ----
// W1F [16kt][64jt][2spl] 1KB frags ; W0F [9][64][2] ; FCF [8][16][2]
// H0P/H1P [2 parity][256 r][256 j] u32 = (bf16hi<<16)|bf16lo
// B0S/B1S [256 jh][4 gate] f32 ; PB [4 parity][16][256] f32
// OCNT: hflags[4][64] (64B spread), fcflags[4][32], epochs[4] (128B spread)
#define OW1F 0u
#define OW0F 2097152u
#define OFCF 3276800u
#define OH0P 3538944u
#define OH1P 4063232u
#define OB0S 4587520u
#define OB1S 4591616u
#define OPB  4595712u
#define OCNT 4661248u

#define MFMA(A,B,C) __builtin_amdgcn_mfma_f32_16x16x32_bf16(A, B, C, 0, 0, 0)

__device__ __forceinline__ short bf_hi(float v) {
    unsigned u = __builtin_bit_cast(unsigned, v);
    unsigned r = (u + 0x7FFFu + ((u >> 16) & 1u)) >> 16;
    return (short)r;
}
__device__ __forceinline__ float bf_f(short h) {
    unsigned u = ((unsigned)(unsigned short)h) << 16;
    return __builtin_bit_cast(float, u);
}
__device__ __forceinline__ float fast_sigmoid(float v) {
    return __builtin_amdgcn_rcpf(1.0f + __expf(-v));
}
__device__ __forceinline__ float fast_tanh(float v) {
    return 1.0f - 2.0f * __builtin_amdgcn_rcpf(1.0f + __expf(2.0f * v));
}

// ---- prep: weight packing identical to R9-R14 (validated); tail extended ----
#define NSH_W1 1048576u
#define NSH_W0 589824u
#define NSH_TOT 1769472u
#define NTAIL 288768u

__global__ __launch_bounds__(256) void prep_kernel(
    const float* __restrict__ Wih0, const float* __restrict__ Whh0,
    const float* __restrict__ bih0, const float* __restrict__ bhh0,
    const float* __restrict__ Wih1, const float* __restrict__ Whh1,
    const float* __restrict__ bih1, const float* __restrict__ bhh1,
    const float* __restrict__ fc1w,
    char* __restrict__ ws)
{
    const unsigned NTOT = NSH_TOT + NTAIL;
    for (unsigned idx = blockIdx.x * blockDim.x + threadIdx.x; idx < NTOT;
         idx += gridDim.x * blockDim.x) {
        if (idx < NSH_TOT) {
            unsigned i2, mode, off;
            if (idx < NSH_W1)               { i2 = idx;                  mode = 0; off = OW1F; }
            else if (idx < NSH_W1 + NSH_W0) { i2 = idx - NSH_W1;         mode = 1; off = OW0F; }
            else                            { i2 = idx - NSH_W1 - NSH_W0; mode = 2; off = OFCF; }
            unsigned frag = i2 >> 9, el = i2 & 511u;
            unsigned lane = el >> 3, e = el & 7u;
            unsigned spl = frag & 1u, jtw = frag >> 1;
            unsigned n = lane & 15u, g = lane >> 4;
            unsigned kw = 4u*g + (e & 3u) + ((e >> 2) << 4);
            float w = 0.f;
            if (mode == 2) {
                unsigned jt = jtw & 15u, kt = frag >> 5;
                unsigned row = jt*16u + n;
                w = fc1w[row*256u + kt*32u + kw];
            } else {
                unsigned jt = jtw & 63u, kt = frag >> 7;
                unsigned row = (n & 3u)*256u + jt*4u + (n >> 2);
                unsigned kg = kt*32u + kw;
                if (mode == 0) {
                    w = (kg < 256u) ? Wih1[row*256u + kg] : Whh1[row*256u + (kg - 256u)];
                } else {
                    if (kt == 0u) w = (kw < 16u) ? Wih0[row*16u + kw] : 0.f;
                    else          w = Whh0[row*256u + (kg - 32u)];
                }
            }
            short hv = bf_hi(w);
            short val = spl ? bf_hi(w - bf_f(hv)) : hv;
            *(short*)(ws + off + (size_t)frag*1024u + (size_t)el*2u) = val;
        } else {
            unsigned f = idx - NSH_TOT;
            if (f < 262144u) {
                ((unsigned*)(ws + OH0P))[f] = 0u;              // h planes
            } else if (f < 263168u) {
                unsigned i3 = f - 262144u, jh = i3 >> 2, gq = i3 & 3u;
                ((float*)(ws + OB0S))[i3] = bih0[gq*256u + jh] + bhh0[gq*256u + jh];
            } else if (f < 264192u) {
                unsigned i3 = f - 263168u, jh = i3 >> 2, gq = i3 & 3u;
                ((float*)(ws + OB1S))[i3] = bih1[gq*256u + jh] + bhh1[gq*256u + jh];
            } else if (f < 280576u) {
                ((float*)(ws + OPB))[f - 264192u] = 0.f;       // PB 4-parity
            } else {
                ((unsigned*)(ws + OCNT))[f - 280576u] = 0u;    // flags/epochs
            }
        }
    }
}

// A-frag pair load from [r][j] packed plane via agent-scope bypass loads
// (sees remote write-through stores, no fence needed, R12-validated)
#define LDH(LO, HI, PL, RT, KB) do { \
    const unsigned long long* bp_ = (const unsigned long long*) \
        ((PL) + ((unsigned)(RT)*16u + (unsigned)n15)*256u \
              + (unsigned)(KB) + 4u*(unsigned)g4); \
    unsigned long long a_ = __hip_atomic_load(bp_,     __ATOMIC_RELAXED, __HIP_MEMORY_SCOPE_AGENT); \
    unsigned long long b_ = __hip_atomic_load(bp_ + 1, __ATOMIC_RELAXED, __HIP_MEMORY_SCOPE_AGENT); \
    unsigned long long c_ = __hip_atomic_load(bp_ + 8, __ATOMIC_RELAXED, __HIP_MEMORY_SCOPE_AGENT); \
    unsigned long long d_ = __hip_atomic_load(bp_ + 9, __ATOMIC_RELAXED, __HIP_MEMORY_SCOPE_AGENT); \
    (LO).x = (unsigned)a_; (LO).y = (unsigned)(a_ >> 32); \
    (LO).z = (unsigned)b_; (LO).w = (unsigned)(b_ >> 32); \
    (HI).x = (unsigned)c_; (HI).y = (unsigned)(c_ >> 32); \
    (HI).z = (unsigned)d_; (HI).w = (unsigned)(d_ >> 32); \
  } while (0)

#define UNPK(AH, AL, LO, HI) do { \
    AH[0]=(short)((LO).x>>16); AH[1]=(short)((LO).y>>16); \
    AH[2]=(short)((LO).z>>16); AH[3]=(short)((LO).w>>16); \
    AH[4]=(short)((HI).x>>16); AH[5]=(short)((HI).y>>16); \
    AH[6]=(short)((HI).z>>16); AH[7]=(short)((HI).w>>16); \
    AL[0]=(short)((LO).x&0xffffu); AL[1]=(short)((LO).y&0xffffu); \
    AL[2]=(short)((LO).z&0xffffu); AL[3]=(short)((LO).w&0xffffu); \
    AL[4]=(short)((HI).x&0xffffu); AL[5]=(short)((HI).y&0xffffu); \
    AL[6]=(short)((HI).z&0xffffu); AL[7]=(short)((HI).w&0xffffu); \
  } while (0)

#define MFMA4(ACC, AH, AL, BH, BL) do { \
    ACC = MFMA(AH, BH, ACC); ACC = MFMA(AL, BH, ACC); \
    ACC = MFMA(AH, BL, ACC); ACC = MFMA(AL, BL, ACC); \
  } while (0)

// 256 blocks x 256 threads, XCD-aligned pairs (xcd = blk&7, pair g = xcd>>1).
// Pair g owns rows [64g,64g+64) for all roles; pairs fully independent.
// Barrier = flag-array: block stores own hflag; aggregator (L1 u==0) wave0
// lane-parallel-polls 64 hflags, stores epoch; wave0-per-block polls epoch.
// FC runs after hflag arrival (off critical path), signals fcflag; out-writer
// polls fcflags; PB is 4-parity (drift <= 3 safe).
template<bool ISL1>
__device__ __forceinline__ void role(
    const float* __restrict__ x,
    const float* __restrict__ fc1b, const float* __restrict__ fc2w,
    const float* __restrict__ fc2b,
    char* __restrict__ ws, float* __restrict__ out,
    int g, int u, bool isOut, int wv, int lane, char* sm)
{
    const int tid  = wv*64 + lane;
    const int jtl  = wv >> 1;
    const int rtl  = wv & 1;
    const int jbase = u * 2;
    const int jt   = jbase + jtl;
    const int rt0w = g*4 + rtl*2;
    const int n15  = lane & 15, g4 = lane >> 4, q = lane & 3;
    const int jh   = jt*4 + (n15 >> 2);
    const int bidp = ISL1 ? ((u >> 4)*32 + (u & 15))
                          : ((u >> 4)*32 + 16 + (u & 15));

    unsigned* const h0p = (unsigned*)(ws + OH0P);
    unsigned* const h1p = (unsigned*)(ws + OH1P);
    unsigned* const hfl = (unsigned*)(ws + OCNT);          // [4][64] stride 16
    unsigned* const ffl = hfl + 4096;                      // [4][32] stride 16
    unsigned* const epo = hfl + 6144;                      // [4] stride 32

    const int fjt = u & 15, frt0 = g*4 + (u >> 4)*2;

    // ---- stage weights into LDS once ----
    if (ISL1) {
        for (int idx = tid; idx < 4096; idx += 256) {
            const int f = idx >> 6, inner = (idx & 63) << 4;
            const int jt2 = f >> 5, kt = (f >> 1) & 15, spl = f & 1;
            const char* src = ws + OW1F
                + ((size_t)((kt*64 + jbase + jt2)*2 + spl))*1024u + (unsigned)inner;
            *(uint4*)(sm + ((size_t)f << 10) + inner) = *(const uint4*)src;
        }
    } else {
        for (int idx = tid; idx < 3328; idx += 256) {
            const int f = idx >> 6, inner = (idx & 63) << 4;
            const char* src;
            if (f < 36) {
                const int jt2 = f / 18, r2 = f - jt2*18, kt = r2 >> 1, spl = r2 & 1;
                src = ws + OW0F
                    + ((size_t)((kt*64 + jbase + jt2)*2 + spl))*1024u + (unsigned)inner;
            } else {
                const int f2 = f - 36, kt = f2 >> 1, spl = f2 & 1;
                src = ws + OFCF
                    + ((size_t)((kt*16 + fjt)*2 + spl))*1024u + (unsigned)inner;
            }
            *(uint4*)(sm + ((size_t)f << 10) + inner) = *(const uint4*)src;
        }
    }
    const char* wlw = sm + ((size_t)jtl * (ISL1 ? 32u : 18u)) * 1024u;
    const char* fcw = sm + 36864u;                 // L0 only
    float* fcs = (float*)(sm + 53248u);            // L0 only, 8KB
    __syncthreads();

    const float4 bsv = *(const float4*)(ws + (ISL1 ? OB1S : OB0S) + (size_t)jh*16u);
    float c0[4] = {0,0,0,0}, c1[4] = {0,0,0,0};
    float fb1 = 0.f, fw2 = 0.f, f2b0 = 0.f;
    if (!ISL1) {
        fb1  = fc1b[fjt*16 + n15];
        fw2  = fc2w[fjt*16 + n15];
        f2b0 = fc2b[0];
    }

    #pragma unroll 1
    for (int i = 0; i < NITER; ++i) {
        const unsigned iu1 = (unsigned)(i + 1);
        const int s = ISL1 ? (i - 1) : i;
        const bool act = (s >= 0) && (s < TSTEPS);
        f4v acc0 = {0,0,0,0}, acc1 = {0,0,0,0};

        // FC h-loads issued early (data is interval-old; consumed post-arrival)
        const int sf = i - 2;
        const bool fact = (!ISL1) && (sf >= 0) && (sf < TSTEPS);
        uint4 fq[2][4];
        if (fact) {
            const unsigned* pf = h1p + (unsigned)(sf & 1) * 65536u;
            #pragma unroll
            for (int kl = 0; kl < 2; ++kl) {
                const int ktf = 2*wv + kl;
                LDH(fq[kl][0], fq[kl][1], pf, frt0,     ktf*32);
                LDH(fq[kl][2], fq[kl][3], pf, frt0 + 1, ktf*32);
            }
        }

        if (act) {
            uint4 hq[4][4];
            if (ISL1) {
                const unsigned* P0 = h0p + (unsigned)(s & 1) * 65536u;        // h0(s)
                const unsigned* P1 = h1p + (unsigned)((s + 1) & 1) * 65536u;  // h1(s-1)
                #pragma unroll
                for (int t = 0; t < 4; ++t) {
                    LDH(hq[t][0], hq[t][1], P0, rt0w,     t*32);
                    LDH(hq[t][2], hq[t][3], P0, rt0w + 1, t*32);
                }
                #pragma unroll
                for (int t = 0; t < 16; ++t) {
                    const int sl = t & 3;
                    s8v bh = *(const s8v*)(wlw + ((size_t)(t*2)    << 10) + (size_t)lane*16u);
                    s8v bl = *(const s8v*)(wlw + ((size_t)(t*2 + 1) << 10) + (size_t)lane*16u);
                    s8v ah, al;
                    UNPK(ah, al, hq[sl][0], hq[sl][1]);
                    MFMA4(acc0, ah, al, bh, bl);
                    UNPK(ah, al, hq[sl][2], hq[sl][3]);
                    MFMA4(acc1, ah, al, bh, bl);
                    if (t + 4 < 16) {
                        const int kn = t + 4;
                        const unsigned* Pn = (kn < 8) ? P0 : P1;
                        const int cb = (kn & 7) * 32;
                        LDH(hq[sl][0], hq[sl][1], Pn, rt0w,     cb);
                        LDH(hq[sl][2], hq[sl][3], Pn, rt0w + 1, cb);
                    }
                }
            } else {
                const unsigned* P0 = h0p + (unsigned)((s + 1) & 1) * 65536u;  // h0(s-1)
                #pragma unroll
                for (int t = 0; t < 4; ++t) {
                    LDH(hq[t][0], hq[t][1], P0, rt0w,     t*32);
                    LDH(hq[t][2], hq[t][3], P0, rt0w + 1, t*32);
                }
                {   // x-projection: B tile 0 = [x(16) | zero-pad]
                    s8v bh = *(const s8v*)(wlw + (size_t)lane*16u);
                    s8v bl = *(const s8v*)(wlw + 1024u + (size_t)lane*16u);
                    #pragma unroll
                    for (int d = 0; d < 2; ++d) {
                        const int r = (rt0w + d)*16 + n15;
                        const float4 xv = *(const float4*)(x + ((size_t)r*TSTEPS + s)*16u
                                                             + 4u*(unsigned)g4);
                        float xs[4] = {xv.x, xv.y, xv.z, xv.w};
                        s8v ah, al;
                        #pragma unroll
                        for (int e = 0; e < 4; ++e) {
                            short hv2 = bf_hi(xs[e]);
                            ah[e] = hv2; al[e] = bf_hi(xs[e] - bf_f(hv2));
                            ah[e + 4] = 0; al[e + 4] = 0;
                        }
                        if (d == 0) MFMA4(acc0, ah, al, bh, bl);
                        else        MFMA4(acc1, ah, al, bh, bl);
                    }
                }
                #pragma unroll
                for (int t = 0; t < 8; ++t) {
                    const int sl = t & 3;
                    s8v bh = *(const s8v*)(wlw + ((size_t)((t+1)*2)     << 10) + (size_t)lane*16u);
                    s8v bl = *(const s8v*)(wlw + ((size_t)((t+1)*2 + 1) << 10) + (size_t)lane*16u);
                    s8v ah, al;
                    UNPK(ah, al, hq[sl][0], hq[sl][1]);
                    MFMA4(acc0, ah, al, bh, bl);
                    UNPK(ah, al, hq[sl][2], hq[sl][3]);
                    MFMA4(acc1, ah, al, bh, bl);
                    if (t + 4 < 8) {
                        const int cb = (t + 4) * 32;
                        LDH(hq[sl][0], hq[sl][1], P0, rt0w,     cb);
                        LDH(hq[sl][2], hq[sl][3], P0, rt0w + 1, cb);
                    }
                }
            }

            // ---- cell update (gate quads), store packed h [r][j] write-through ----
            unsigned* hwp = (ISL1 ? h1p : h0p) + (unsigned)(s & 1) * 65536u;
            #pragma unroll
            for (int d = 0; d < 2; ++d) {
                const int rt = rt0w + d;
                f4v av = d ? acc1 : acc0;
                float* cc = d ? c1 : c0;
                unsigned pk[4];
                #pragma unroll
                for (int e = 0; e < 4; ++e) {
                    float v0 = av[e];
                    float v1 = __shfl_xor(v0, 1);
                    float v2 = __shfl_xor(v0, 2);
                    float v3 = __shfl_xor(v1, 2);
                    float gi = (q==0)? v0 : (q==1)? v1 : (q==2)? v2 : v3;
                    float gf = (q==0)? v1 : (q==1)? v0 : (q==2)? v3 : v2;
                    float gg = (q==0)? v2 : (q==1)? v3 : (q==2)? v0 : v1;
                    float go = (q==0)? v3 : (q==1)? v2 : (q==2)? v1 : v0;
                    float ig = fast_sigmoid(gi + bsv.x);
                    float fg = fast_sigmoid(gf + bsv.y);
                    float gt = fast_tanh   (gg + bsv.z);
                    float og = fast_sigmoid(go + bsv.w);
                    float cn = fg * cc[e] + ig * gt;
                    cc[e] = cn;
                    float h = og * fast_tanh(cn);
                    short hv = bf_hi(h);
                    short lv = bf_hi(h - bf_f(hv));
                    pk[e] = ((unsigned)(unsigned short)hv << 16) | (unsigned)(unsigned short)lv;
                }
                if (q == 0) {
                    #pragma unroll
                    for (int e = 0; e < 4; ++e) {
                        const int r = rt*16 + 4*g4 + e;
                        __hip_atomic_store(hwp + (unsigned)r*256u + (unsigned)jh, pk[e],
                                           __ATOMIC_RELAXED, __HIP_MEMORY_SCOPE_AGENT);
                    }
                }
            }
        }

        // ---- arrival: drain h stores, then store own hflag ----
        __syncthreads();
        if (tid == 0)
            __hip_atomic_store(hfl + (g << 10) + (bidp << 4), iu1,
                               __ATOMIC_RELAXED, __HIP_MEMORY_SCOPE_AGENT);

        if (!ISL1) {
            // ---- out: per-pair fc2 reduce for step i-3 (wave0, after fcflag poll) ----
            if (isOut && i >= 3 && wv == 0) {
                for (;;) {
                    unsigned v = __hip_atomic_load(ffl + (g << 9) + ((lane & 31) << 4),
                                                   __ATOMIC_RELAXED, __HIP_MEMORY_SCOPE_AGENT);
                    if (__all((int)(v >= (unsigned)i))) break;
                    __builtin_amdgcn_s_sleep(1);
                }
                const int tt = i - 3;
                const int r = g*64 + lane;
                const unsigned* pb2 = (const unsigned*)(ws + OPB)
                                      + (unsigned)((i - 1) & 3)*4096u;
                float ssum = f2b0;
                #pragma unroll
                for (int jx = 0; jx < 16; ++jx) {
                    unsigned uv = __hip_atomic_load(pb2 + jx*256 + r,
                                                    __ATOMIC_RELAXED, __HIP_MEMORY_SCOPE_AGENT);
                    ssum += __builtin_bit_cast(float, uv);
                }
                __hip_atomic_store((unsigned*)&out[(size_t)r*TSTEPS + tt],
                                   __builtin_bit_cast(unsigned, ssum),
                                   __ATOMIC_RELAXED, __HIP_MEMORY_SCOPE_AGENT);
            }
            // ---- FC: fc1 + relu + fc2 partials for step i-2 (off critical path) ----
            if (fact) {
                f4v fa0 = {0,0,0,0}, fa1 = {0,0,0,0};
                #pragma unroll
                for (int kl = 0; kl < 2; ++kl) {
                    const int ktf = 2*wv + kl;
                    s8v fh = *(const s8v*)(fcw + ((size_t)(ktf*2)     << 10) + (size_t)lane*16u);
                    s8v fl = *(const s8v*)(fcw + ((size_t)(ktf*2 + 1) << 10) + (size_t)lane*16u);
                    s8v ah, al;
                    UNPK(ah, al, fq[kl][0], fq[kl][1]);
                    MFMA4(fa0, ah, al, fh, fl);
                    UNPK(ah, al, fq[kl][2], fq[kl][3]);
                    MFMA4(fa1, ah, al, fh, fl);
                }
                *(f4v*)&fcs[(wv*2 + 0)*256 + lane*4] = fa0;
                *(f4v*)&fcs[(wv*2 + 1)*256 + lane*4] = fa1;
            }
            __syncthreads();
            if (fact && wv == 0) {
                #pragma unroll
                for (int d = 0; d < 2; ++d) {
                    f4v av = {0,0,0,0};
                    #pragma unroll
                    for (int w2 = 0; w2 < 4; ++w2)
                        av = av + *(const f4v*)&fcs[(w2*2 + d)*256 + lane*4];
                    float pe[4];
                    #pragma unroll
                    for (int e = 0; e < 4; ++e) {
                        float v = av[e] + fb1;
                        v = v > 0.f ? v : 0.f;
                        float p = v * fw2;
                        p += __shfl_xor(p, 1);
                        p += __shfl_xor(p, 2);
                        p += __shfl_xor(p, 4);
                        p += __shfl_xor(p, 8);
                        pe[e] = p;
                    }
                    if (n15 == 0) {
                        unsigned* pb = (unsigned*)(ws + OPB) + (unsigned)(i & 3)*4096u
                                       + (unsigned)(fjt*256 + (frt0 + d)*16 + 4*g4);
                        unsigned long long lo =
                            ((unsigned long long)__builtin_bit_cast(unsigned, pe[1]) << 32)
                            | __builtin_bit_cast(unsigned, pe[0]);
                        unsigned long long hi =
                            ((unsigned long long)__builtin_bit_cast(unsigned, pe[3]) << 32)
                            | __builtin_bit_cast(unsigned, pe[2]);
                        __hip_atomic_store((unsigned long long*)pb,       lo, __ATOMIC_RELAXED, __HIP_MEMORY_SCOPE_AGENT);
                        __hip_atomic_store((unsigned long long*)(pb + 2), hi, __ATOMIC_RELAXED, __HIP_MEMORY_SCOPE_AGENT);
                    }
                }
            }
            __syncthreads();   // drain PB/out stores
            if (tid == 0)
                __hip_atomic_store(ffl + (g << 9) + (u << 4), iu1,
                                   __ATOMIC_RELAXED, __HIP_MEMORY_SCOPE_AGENT);
        }

        // ---- epoch: aggregator polls 64 hflags lane-parallel; rest poll epoch ----
        if (ISL1 && u == 0) {
            if (wv == 0) {
                for (;;) {
                    unsigned v = __hip_atomic_load(hfl + (g << 10) + (lane << 4),
                                                   __ATOMIC_RELAXED, __HIP_MEMORY_SCOPE_AGENT);
                    if (__all((int)(v >= iu1))) break;
                    __builtin_amdgcn_s_sleep(1);
                }
                if (lane == 0)
                    __hip_atomic_store(epo + (g << 5), iu1,
                                       __ATOMIC_RELAXED, __HIP_MEMORY_SCOPE_AGENT);
            }
            __syncthreads();
        } else {
            if (wv == 0) {
                while (__hip_atomic_load(epo + (g << 5), __ATOMIC_RELAXED,
                                         __HIP_MEMORY_SCOPE_AGENT) < iu1)
                    __builtin_amdgcn_s_sleep(1);
            }
            __syncthreads();
        }
    }
}

__global__ __launch_bounds__(256, 1) void lstm_mfma(
    const float* __restrict__ x, const float* __restrict__ fc1b,
    const float* __restrict__ fc2w, const float* __restrict__ fc2b,
    char* __restrict__ ws, float* __restrict__ out)
{
    __shared__ __align__(16) char sm[65536];
    const int tid  = threadIdx.x;
    const int lane = tid & 63;
    const int wv   = __builtin_amdgcn_readfirstlane(tid >> 6);
    const int blk  = blockIdx.x;
    const int xcd  = blk & 7, slot = blk >> 3;
    const int g    = xcd >> 1, side = xcd & 1;
    if (slot < 16)
        role<true >(x, fc1b, fc2w, fc2b, ws, out, g, side*16 + slot, false,
                    wv, lane, sm);
    else
        role<false>(x, fc1b, fc2w, fc2b, ws, out, g, side*16 + (slot - 16),
                    (slot == 16) && (side == 0), wv, lane, sm);
}

extern "C" void kernel_launch(void* const* d_in, const int* in_sizes, int n_in,
                              void* d_out, int out_size, void* d_ws, size_t ws_size,
                              hipStream_t stream)
{
    const float* x    = (const float*)d_in[0];
    const float* Wih0 = (const float*)d_in[1];
    const float* Whh0 = (const float*)d_in[2];
    const float* bih0 = (const float*)d_in[3];
    const float* bhh0 = (const float*)d_in[4];
    const float* Wih1 = (const float*)d_in[5];
    const float* Whh1 = (const float*)d_in[6];
    const float* bih1 = (const float*)d_in[7];
    const float* bhh1 = (const float*)d_in[8];
    const float* fc1w = (const float*)d_in[9];
    const float* fc1b = (const float*)d_in[10];
    const float* fc2w = (const float*)d_in[11];
    const float* fc2b = (const float*)d_in[12];
    char*  ws  = (char*)d_ws;
    float* out = (float*)d_out;

    prep_kernel<<<1024, 256, 0, stream>>>(Wih0, Whh0, bih0, bhh0,
                                          Wih1, Whh1, bih1, bhh1, fc1w, ws);

    void* args[] = {(void*)&x, (void*)&fc1b, (void*)&fc2w, (void*)&fc2b,
                    (void*)&ws, (void*)&out};
    hipLaunchCooperativeKernel((const void*)lstm_mfma, dim3(256), dim3(256),
                               args, 0, stream);
}

// Round 17
// 11511.703 us; speedup vs baseline: 2.7492x; 1.4602x over previous
//
#include <hip/hip_runtime.h>
#include <math.h>

#define TSTEPS 1024
#define NITER  1027

typedef __attribute__((ext_vector_type(8))) short s8v;   // bf16x8 MFMA frag
typedef __attribute__((ext_vector_type(4))) float f4v;   // f32x4 acc

// ---- ws byte offsets ----
// W1F [16kt][64jt][2spl] 1KB frags ; W0F [9][64][2] ; FCF [8][16][2]
// H0P/H1P [2 parity][256 r][256 j] u32 = (bf16hi<<16)|bf16lo
// B0S/B1S [256 jh][4 gate] f32 ; PB [4 parity][16][256] f32
// OCNT: hflags[4][64] (64B spread), fcflags[4][32], epochs[4] (128B spread)
#define OW1F 0u
#define OW0F 2097152u
#define OFCF 3276800u
#define OH0P 3538944u
#define OH1P 4063232u
#define OB0S 4587520u
#define OB1S 4591616u
#define OPB  4595712u
#define OCNT 4661248u

#define MFMA(A,B,C) __builtin_amdgcn_mfma_f32_16x16x32_bf16(A, B, C, 0, 0, 0)

__device__ __forceinline__ short bf_hi(float v) {
    unsigned u = __builtin_bit_cast(unsigned, v);
    unsigned r = (u + 0x7FFFu + ((u >> 16) & 1u)) >> 16;
    return (short)r;
}
__device__ __forceinline__ float bf_f(short h) {
    unsigned u = ((unsigned)(unsigned short)h) << 16;
    return __builtin_bit_cast(float, u);
}
__device__ __forceinline__ float fast_sigmoid(float v) {
    return __builtin_amdgcn_rcpf(1.0f + __expf(-v));
}
__device__ __forceinline__ float fast_tanh(float v) {
    return 1.0f - 2.0f * __builtin_amdgcn_rcpf(1.0f + __expf(2.0f * v));
}

// ---- prep: identical to R9-R15 (validated) ----
#define NSH_W1 1048576u
#define NSH_W0 589824u
#define NSH_TOT 1769472u
#define NTAIL 288768u

__global__ __launch_bounds__(256) void prep_kernel(
    const float* __restrict__ Wih0, const float* __restrict__ Whh0,
    const float* __restrict__ bih0, const float* __restrict__ bhh0,
    const float* __restrict__ Wih1, const float* __restrict__ Whh1,
    const float* __restrict__ bih1, const float* __restrict__ bhh1,
    const float* __restrict__ fc1w,
    char* __restrict__ ws)
{
    const unsigned NTOT = NSH_TOT + NTAIL;
    for (unsigned idx = blockIdx.x * blockDim.x + threadIdx.x; idx < NTOT;
         idx += gridDim.x * blockDim.x) {
        if (idx < NSH_TOT) {
            unsigned i2, mode, off;
            if (idx < NSH_W1)               { i2 = idx;                  mode = 0; off = OW1F; }
            else if (idx < NSH_W1 + NSH_W0) { i2 = idx - NSH_W1;         mode = 1; off = OW0F; }
            else                            { i2 = idx - NSH_W1 - NSH_W0; mode = 2; off = OFCF; }
            unsigned frag = i2 >> 9, el = i2 & 511u;
            unsigned lane = el >> 3, e = el & 7u;
            unsigned spl = frag & 1u, jtw = frag >> 1;
            unsigned n = lane & 15u, g = lane >> 4;
            unsigned kw = 4u*g + (e & 3u) + ((e >> 2) << 4);
            float w = 0.f;
            if (mode == 2) {
                unsigned jt = jtw & 15u, kt = frag >> 5;
                unsigned row = jt*16u + n;
                w = fc1w[row*256u + kt*32u + kw];
            } else {
                unsigned jt = jtw & 63u, kt = frag >> 7;
                unsigned row = (n & 3u)*256u + jt*4u + (n >> 2);
                unsigned kg = kt*32u + kw;
                if (mode == 0) {
                    w = (kg < 256u) ? Wih1[row*256u + kg] : Whh1[row*256u + (kg - 256u)];
                } else {
                    if (kt == 0u) w = (kw < 16u) ? Wih0[row*16u + kw] : 0.f;
                    else          w = Whh0[row*256u + (kg - 32u)];
                }
            }
            short hv = bf_hi(w);
            short val = spl ? bf_hi(w - bf_f(hv)) : hv;
            *(short*)(ws + off + (size_t)frag*1024u + (size_t)el*2u) = val;
        } else {
            unsigned f = idx - NSH_TOT;
            if (f < 262144u) {
                ((unsigned*)(ws + OH0P))[f] = 0u;              // h planes
            } else if (f < 263168u) {
                unsigned i3 = f - 262144u, jh = i3 >> 2, gq = i3 & 3u;
                ((float*)(ws + OB0S))[i3] = bih0[gq*256u + jh] + bhh0[gq*256u + jh];
            } else if (f < 264192u) {
                unsigned i3 = f - 263168u, jh = i3 >> 2, gq = i3 & 3u;
                ((float*)(ws + OB1S))[i3] = bih1[gq*256u + jh] + bhh1[gq*256u + jh];
            } else if (f < 280576u) {
                ((float*)(ws + OPB))[f - 264192u] = 0.f;       // PB 4-parity
            } else {
                ((unsigned*)(ws + OCNT))[f - 280576u] = 0u;    // flags/epochs
            }
        }
    }
}

// A-frag pair load from [r][j] packed plane via agent-scope bypass loads
#define LDH(LO, HI, PL, RT, KB) do { \
    const unsigned long long* bp_ = (const unsigned long long*) \
        ((PL) + ((unsigned)(RT)*16u + (unsigned)n15)*256u \
              + (unsigned)(KB) + 4u*(unsigned)g4); \
    unsigned long long a_ = __hip_atomic_load(bp_,     __ATOMIC_RELAXED, __HIP_MEMORY_SCOPE_AGENT); \
    unsigned long long b_ = __hip_atomic_load(bp_ + 1, __ATOMIC_RELAXED, __HIP_MEMORY_SCOPE_AGENT); \
    unsigned long long c_ = __hip_atomic_load(bp_ + 8, __ATOMIC_RELAXED, __HIP_MEMORY_SCOPE_AGENT); \
    unsigned long long d_ = __hip_atomic_load(bp_ + 9, __ATOMIC_RELAXED, __HIP_MEMORY_SCOPE_AGENT); \
    (LO).x = (unsigned)a_; (LO).y = (unsigned)(a_ >> 32); \
    (LO).z = (unsigned)b_; (LO).w = (unsigned)(b_ >> 32); \
    (HI).x = (unsigned)c_; (HI).y = (unsigned)(c_ >> 32); \
    (HI).z = (unsigned)d_; (HI).w = (unsigned)(d_ >> 32); \
  } while (0)

#define UNPK(AH, AL, LO, HI) do { \
    AH[0]=(short)((LO).x>>16); AH[1]=(short)((LO).y>>16); \
    AH[2]=(short)((LO).z>>16); AH[3]=(short)((LO).w>>16); \
    AH[4]=(short)((HI).x>>16); AH[5]=(short)((HI).y>>16); \
    AH[6]=(short)((HI).z>>16); AH[7]=(short)((HI).w>>16); \
    AL[0]=(short)((LO).x&0xffffu); AL[1]=(short)((LO).y&0xffffu); \
    AL[2]=(short)((LO).z&0xffffu); AL[3]=(short)((LO).w&0xffffu); \
    AL[4]=(short)((HI).x&0xffffu); AL[5]=(short)((HI).y&0xffffu); \
    AL[6]=(short)((HI).z&0xffffu); AL[7]=(short)((HI).w&0xffffu); \
  } while (0)

#define MFMA4(ACC, AH, AL, BH, BL) do { \
    ACC = MFMA(AH, BH, ACC); ACC = MFMA(AL, BH, ACC); \
    ACC = MFMA(AH, BL, ACC); ACC = MFMA(AL, BL, ACC); \
  } while (0)

// pin a uint4's components in VGPRs (scalar ties only; vector ties unsupported)
#define OPAQUE4(V) asm volatile("" : "+v"((V).x), "+v"((V).y), "+v"((V).z), "+v"((V).w))

// 256 blocks x 256 threads, XCD-aligned pairs (pair g = (blk&7)>>1).
// Wave map: wv -> kh = wv&1 (K-half), rtl = wv>>1 (rt pair).
// Each wave covers BOTH j-tiles for its K-half -> block read volume halves;
// kh1 partials joined to kh0 via LDS exchange.
// L1 LDS: 60KB weights (kt0-14) + 4KB exchange; kt15 frags in VGPRs.
// L0 LDS: 36KB weights + 16KB FC + 8KB fcs (exchange + FC reduce).
// Flags/epoch/out/FC protocol identical to R15 (validated).
template<bool ISL1>
__device__ __forceinline__ void role(
    const float* __restrict__ x,
    const float* __restrict__ fc1b, const float* __restrict__ fc2w,
    const float* __restrict__ fc2b,
    char* __restrict__ ws, float* __restrict__ out,
    int g, int u, bool isOut, int wv, int lane, char* sm)
{
    const int tid  = wv*64 + lane;
    const int kh   = wv & 1;
    const int rtl  = wv >> 1;
    const int jbase = u * 2;
    const int rt0w = g*4 + rtl*2;
    const int n15  = lane & 15, g4 = lane >> 4, q = lane & 3;
    const int bidp = ISL1 ? ((u >> 4)*32 + (u & 15))
                          : ((u >> 4)*32 + 16 + (u & 15));

    unsigned* const h0p = (unsigned*)(ws + OH0P);
    unsigned* const h1p = (unsigned*)(ws + OH1P);
    unsigned* const hfl = (unsigned*)(ws + OCNT);          // [4][64] stride 16
    unsigned* const ffl = hfl + 4096;                      // [4][32] stride 16
    unsigned* const epo = hfl + 6144;                      // [4] stride 32

    const int fjt = u & 15, frt0 = g*4 + (u >> 4)*2;

    // ---- stage weights into LDS once ----
    if (ISL1) {
        // [jt2(2)][kt(15)][spl(2)] 1KB frags = 60KB (kt15 goes to VGPRs)
        for (int idx = tid; idx < 3840; idx += 256) {
            const int f = idx >> 6, inner = (idx & 63) << 4;
            const int jt2 = (f >= 30) ? 1 : 0;
            const int r2 = f - jt2*30, kt = r2 >> 1, spl = r2 & 1;
            const char* src = ws + OW1F
                + ((size_t)((kt*64 + jbase + jt2)*2 + spl))*1024u + (unsigned)inner;
            *(uint4*)(sm + ((size_t)f << 10) + inner) = *(const uint4*)src;
        }
    } else {
        // [jt2(2)][kt(9)][spl(2)] = 36KB ; FC [kt(8)][spl(2)] at 36KB = 16KB
        for (int idx = tid; idx < 3328; idx += 256) {
            const int f = idx >> 6, inner = (idx & 63) << 4;
            const char* src;
            if (f < 36) {
                const int jt2 = f / 18, r2 = f - jt2*18, kt = r2 >> 1, spl = r2 & 1;
                src = ws + OW0F
                    + ((size_t)((kt*64 + jbase + jt2)*2 + spl))*1024u + (unsigned)inner;
            } else {
                const int f2 = f - 36, kt = f2 >> 1, spl = f2 & 1;
                src = ws + OFCF
                    + ((size_t)((kt*16 + fjt)*2 + spl))*1024u + (unsigned)inner;
            }
            *(uint4*)(sm + ((size_t)f << 10) + inner) = *(const uint4*)src;
        }
    }
    // kt15 weight frags in registers (L1 only); per-component asm opacification
    // so the ws-alias can't sink these loads into the loop (R10/R16 lesson).
    s8v B15h[2] = {}, B15l[2] = {};
    if (ISL1) {
        #pragma unroll
        for (int jt2 = 0; jt2 < 2; ++jt2) {
            const char* fb = ws + OW1F
                + ((size_t)((15*64 + jbase + jt2)*2))*1024u + (size_t)lane*16u;
            uint4 th = *(const uint4*)fb;
            uint4 tl = *(const uint4*)(fb + 1024u);
            OPAQUE4(th);
            OPAQUE4(tl);
            B15h[jt2] = __builtin_bit_cast(s8v, th);
            B15l[jt2] = __builtin_bit_cast(s8v, tl);
        }
    }
    float* xch = (float*)(sm + 61440);             // L1 exchange, 4KB
    const char* fcw = sm + 36864u;                 // L0 only
    float* fcs = (float*)(sm + 53248);             // L0: exchange + FC, 8KB
    __syncthreads();

    const int jhA = jbase*4 + (n15 >> 2);
    const int jhB = (jbase + 1)*4 + (n15 >> 2);
    const float4 bsvA = *(const float4*)(ws + (ISL1 ? OB1S : OB0S) + (size_t)jhA*16u);
    const float4 bsvB = *(const float4*)(ws + (ISL1 ? OB1S : OB0S) + (size_t)jhB*16u);
    float cst[2][2][4] = {};                       // c-state (kh0 waves only)
    float fb1 = 0.f, fw2 = 0.f, f2b0 = 0.f;
    if (!ISL1) {
        fb1  = fc1b[fjt*16 + n15];
        fw2  = fc2w[fjt*16 + n15];
        f2b0 = fc2b[0];
    }

    #pragma unroll 1
    for (int i = 0; i < NITER; ++i) {
        const unsigned iu1 = (unsigned)(i + 1);
        const int s = ISL1 ? (i - 1) : i;
        const bool act = (s >= 0) && (s < TSTEPS);

        // FC h-loads issued early (consumed post-arrival; interval-old data)
        const int sf = i - 2;
        const bool fact = (!ISL1) && (sf >= 0) && (sf < TSTEPS);
        uint4 fq[2][4];
        if (fact) {
            const unsigned* pf = h1p + (unsigned)(sf & 1) * 65536u;
            #pragma unroll
            for (int kl = 0; kl < 2; ++kl) {
                const int ktf = 2*wv + kl;
                LDH(fq[kl][0], fq[kl][1], pf, frt0,     ktf*32);
                LDH(fq[kl][2], fq[kl][3], pf, frt0 + 1, ktf*32);
            }
        }

        f4v acc[2][2] = {{{0,0,0,0},{0,0,0,0}},{{0,0,0,0},{0,0,0,0}}};

        if (act) {
            if (ISL1) {
                // kh0: h0(s) kt0-7 ; kh1: h1(s-1) kt8-15
                const unsigned* PL = kh ? (h1p + (unsigned)((s + 1) & 1) * 65536u)
                                        : (h0p + (unsigned)(s & 1) * 65536u);
                uint4 hq[8][2][2];
                #pragma unroll
                for (int t = 0; t < 8; ++t) {
                    LDH(hq[t][0][0], hq[t][0][1], PL, rt0w,     t*32);
                    LDH(hq[t][1][0], hq[t][1][1], PL, rt0w + 1, t*32);
                }
                #pragma unroll
                for (int t = 0; t < 8; ++t) {
                    s8v ah[2], al[2];
                    UNPK(ah[0], al[0], hq[t][0][0], hq[t][0][1]);
                    UNPK(ah[1], al[1], hq[t][1][0], hq[t][1][1]);
                    #pragma unroll
                    for (int jt2 = 0; jt2 < 2; ++jt2) {
                        s8v bh, bl;
                        if (kh && t == 7) { bh = B15h[jt2]; bl = B15l[jt2]; }
                        else {
                            const int ktg = kh*8 + t;
                            const char* fb = sm + ((size_t)(jt2*30 + ktg*2) << 10)
                                             + (size_t)lane*16u;
                            bh = *(const s8v*)fb;
                            bl = *(const s8v*)(fb + 1024u);
                        }
                        MFMA4(acc[jt2][0], ah[0], al[0], bh, bl);
                        MFMA4(acc[jt2][1], ah[1], al[1], bh, bl);
                    }
                }
            } else {
                // kh0: x-tile + h-tiles 0-3 ; kh1: h-tiles 4-7 (of h0(s-1))
                const unsigned* P0 = h0p + (unsigned)((s + 1) & 1) * 65536u;
                uint4 hq[4][2][2];
                #pragma unroll
                for (int t = 0; t < 4; ++t) {
                    const int ht = kh*4 + t;
                    LDH(hq[t][0][0], hq[t][0][1], P0, rt0w,     ht*32);
                    LDH(hq[t][1][0], hq[t][1][1], P0, rt0w + 1, ht*32);
                }
                if (!kh) {   // x-projection (B tile 0): [x(16) | zero-pad]
                    #pragma unroll
                    for (int rtd = 0; rtd < 2; ++rtd) {
                        const int r = (rt0w + rtd)*16 + n15;
                        const float4 xv = *(const float4*)(x + ((size_t)r*TSTEPS + s)*16u
                                                             + 4u*(unsigned)g4);
                        float xs[4] = {xv.x, xv.y, xv.z, xv.w};
                        s8v ah, al;
                        #pragma unroll
                        for (int e = 0; e < 4; ++e) {
                            short hv2 = bf_hi(xs[e]);
                            ah[e] = hv2; al[e] = bf_hi(xs[e] - bf_f(hv2));
                            ah[e + 4] = 0; al[e + 4] = 0;
                        }
                        #pragma unroll
                        for (int jt2 = 0; jt2 < 2; ++jt2) {
                            const char* fb = sm + ((size_t)(jt2*18) << 10)
                                             + (size_t)lane*16u;
                            s8v bh = *(const s8v*)fb;
                            s8v bl = *(const s8v*)(fb + 1024u);
                            MFMA4(acc[jt2][rtd], ah, al, bh, bl);
                        }
                    }
                }
                #pragma unroll
                for (int t = 0; t < 4; ++t) {
                    s8v ah[2], al[2];
                    UNPK(ah[0], al[0], hq[t][0][0], hq[t][0][1]);
                    UNPK(ah[1], al[1], hq[t][1][0], hq[t][1][1]);
                    const int btile = 1 + kh*4 + t;
                    #pragma unroll
                    for (int jt2 = 0; jt2 < 2; ++jt2) {
                        const char* fb = sm + ((size_t)(jt2*18 + btile*2) << 10)
                                         + (size_t)lane*16u;
                        s8v bh = *(const s8v*)fb;
                        s8v bl = *(const s8v*)(fb + 1024u);
                        MFMA4(acc[jt2][0], ah[0], al[0], bh, bl);
                        MFMA4(acc[jt2][1], ah[1], al[1], bh, bl);
                    }
                }
            }

            // ---- kh1 -> kh0 partial exchange ----
            if (ISL1) {
                if (kh == 1 && rtl == 0) {
                    #pragma unroll
                    for (int jt2 = 0; jt2 < 2; ++jt2)
                        #pragma unroll
                        for (int rtd = 0; rtd < 2; ++rtd)
                            *(f4v*)&xch[(jt2*2 + rtd)*256 + lane*4] = acc[jt2][rtd];
                }
                __syncthreads();
                if (kh == 0 && rtl == 0) {
                    #pragma unroll
                    for (int jt2 = 0; jt2 < 2; ++jt2)
                        #pragma unroll
                        for (int rtd = 0; rtd < 2; ++rtd)
                            acc[jt2][rtd] = acc[jt2][rtd]
                                + *(const f4v*)&xch[(jt2*2 + rtd)*256 + lane*4];
                }
                __syncthreads();
                if (kh == 1 && rtl == 1) {
                    #pragma unroll
                    for (int jt2 = 0; jt2 < 2; ++jt2)
                        #pragma unroll
                        for (int rtd = 0; rtd < 2; ++rtd)
                            *(f4v*)&xch[(jt2*2 + rtd)*256 + lane*4] = acc[jt2][rtd];
                }
                __syncthreads();
                if (kh == 0 && rtl == 1) {
                    #pragma unroll
                    for (int jt2 = 0; jt2 < 2; ++jt2)
                        #pragma unroll
                        for (int rtd = 0; rtd < 2; ++rtd)
                            acc[jt2][rtd] = acc[jt2][rtd]
                                + *(const f4v*)&xch[(jt2*2 + rtd)*256 + lane*4];
                }
            } else {
                if (kh == 1) {
                    #pragma unroll
                    for (int jt2 = 0; jt2 < 2; ++jt2)
                        #pragma unroll
                        for (int rtd = 0; rtd < 2; ++rtd)
                            *(f4v*)&fcs[(rtl*4 + jt2*2 + rtd)*256 + lane*4] = acc[jt2][rtd];
                }
                __syncthreads();
                if (kh == 0) {
                    #pragma unroll
                    for (int jt2 = 0; jt2 < 2; ++jt2)
                        #pragma unroll
                        for (int rtd = 0; rtd < 2; ++rtd)
                            acc[jt2][rtd] = acc[jt2][rtd]
                                + *(const f4v*)&fcs[(rtl*4 + jt2*2 + rtd)*256 + lane*4];
                }
            }

            // ---- cell update (kh0 waves; both jt, both rt), packed h stores ----
            if (kh == 0) {
                unsigned* hwp = (ISL1 ? h1p : h0p) + (unsigned)(s & 1) * 65536u;
                #pragma unroll
                for (int jt2 = 0; jt2 < 2; ++jt2) {
                    const float4 bsv = jt2 ? bsvB : bsvA;
                    const int jh2 = jt2 ? jhB : jhA;
                    #pragma unroll
                    for (int rtd = 0; rtd < 2; ++rtd) {
                        const int rt = rt0w + rtd;
                        f4v av = acc[jt2][rtd];
                        unsigned pk[4];
                        #pragma unroll
                        for (int e = 0; e < 4; ++e) {
                            float v0 = av[e];
                            float v1 = __shfl_xor(v0, 1);
                            float v2 = __shfl_xor(v0, 2);
                            float v3 = __shfl_xor(v1, 2);
                            float gi = (q==0)? v0 : (q==1)? v1 : (q==2)? v2 : v3;
                            float gf = (q==0)? v1 : (q==1)? v0 : (q==2)? v3 : v2;
                            float gg = (q==0)? v2 : (q==1)? v3 : (q==2)? v0 : v1;
                            float go = (q==0)? v3 : (q==1)? v2 : (q==2)? v1 : v0;
                            float ig = fast_sigmoid(gi + bsv.x);
                            float fg = fast_sigmoid(gf + bsv.y);
                            float gt = fast_tanh   (gg + bsv.z);
                            float og = fast_sigmoid(go + bsv.w);
                            float cn = fg * cst[jt2][rtd][e] + ig * gt;
                            cst[jt2][rtd][e] = cn;
                            float h = og * fast_tanh(cn);
                            short hv = bf_hi(h);
                            short lv = bf_hi(h - bf_f(hv));
                            pk[e] = ((unsigned)(unsigned short)hv << 16)
                                    | (unsigned)(unsigned short)lv;
                        }
                        if (q == 0) {
                            #pragma unroll
                            for (int e = 0; e < 4; ++e) {
                                const int r = rt*16 + 4*g4 + e;
                                __hip_atomic_store(hwp + (unsigned)r*256u + (unsigned)jh2,
                                                   pk[e], __ATOMIC_RELAXED,
                                                   __HIP_MEMORY_SCOPE_AGENT);
                            }
                        }
                    }
                }
            }
        }

        // ---- arrival: drain h stores, then store own hflag ----
        __syncthreads();
        if (tid == 0)
            __hip_atomic_store(hfl + (g << 10) + (bidp << 4), iu1,
                               __ATOMIC_RELAXED, __HIP_MEMORY_SCOPE_AGENT);

        if (!ISL1) {
            // ---- out: per-pair fc2 reduce for step i-3 (wave0, fcflag poll) ----
            if (isOut && i >= 3 && wv == 0) {
                for (;;) {
                    unsigned v = __hip_atomic_load(ffl + (g << 9) + ((lane & 31) << 4),
                                                   __ATOMIC_RELAXED, __HIP_MEMORY_SCOPE_AGENT);
                    if (__all((int)(v >= (unsigned)i))) break;
                    __builtin_amdgcn_s_sleep(1);
                }
                const int tt = i - 3;
                const int r = g*64 + lane;
                const unsigned* pb2 = (const unsigned*)(ws + OPB)
                                      + (unsigned)((i - 1) & 3)*4096u;
                float ssum = f2b0;
                #pragma unroll
                for (int jx = 0; jx < 16; ++jx) {
                    unsigned uv = __hip_atomic_load(pb2 + jx*256 + r,
                                                    __ATOMIC_RELAXED, __HIP_MEMORY_SCOPE_AGENT);
                    ssum += __builtin_bit_cast(float, uv);
                }
                __hip_atomic_store((unsigned*)&out[(size_t)r*TSTEPS + tt],
                                   __builtin_bit_cast(unsigned, ssum),
                                   __ATOMIC_RELAXED, __HIP_MEMORY_SCOPE_AGENT);
            }
            // ---- FC: fc1 + relu + fc2 partials for step i-2 ----
            if (fact) {
                f4v fa0 = {0,0,0,0}, fa1 = {0,0,0,0};
                #pragma unroll
                for (int kl = 0; kl < 2; ++kl) {
                    const int ktf = 2*wv + kl;
                    s8v fh = *(const s8v*)(fcw + ((size_t)(ktf*2)     << 10) + (size_t)lane*16u);
                    s8v fl = *(const s8v*)(fcw + ((size_t)(ktf*2 + 1) << 10) + (size_t)lane*16u);
                    s8v ah, al;
                    UNPK(ah, al, fq[kl][0], fq[kl][1]);
                    MFMA4(fa0, ah, al, fh, fl);
                    UNPK(ah, al, fq[kl][2], fq[kl][3]);
                    MFMA4(fa1, ah, al, fh, fl);
                }
                *(f4v*)&fcs[(wv*2 + 0)*256 + lane*4] = fa0;
                *(f4v*)&fcs[(wv*2 + 1)*256 + lane*4] = fa1;
            }
            __syncthreads();
            if (fact && wv == 0) {
                #pragma unroll
                for (int d = 0; d < 2; ++d) {
                    f4v av = {0,0,0,0};
                    #pragma unroll
                    for (int w2 = 0; w2 < 4; ++w2)
                        av = av + *(const f4v*)&fcs[(w2*2 + d)*256 + lane*4];
                    float pe[4];
                    #pragma unroll
                    for (int e = 0; e < 4; ++e) {
                        float v = av[e] + fb1;
                        v = v > 0.f ? v : 0.f;
                        float p = v * fw2;
                        p += __shfl_xor(p, 1);
                        p += __shfl_xor(p, 2);
                        p += __shfl_xor(p, 4);
                        p += __shfl_xor(p, 8);
                        pe[e] = p;
                    }
                    if (n15 == 0) {
                        unsigned* pb = (unsigned*)(ws + OPB) + (unsigned)(i & 3)*4096u
                                       + (unsigned)(fjt*256 + (frt0 + d)*16 + 4*g4);
                        unsigned long long lo =
                            ((unsigned long long)__builtin_bit_cast(unsigned, pe[1]) << 32)
                            | __builtin_bit_cast(unsigned, pe[0]);
                        unsigned long long hi =
                            ((unsigned long long)__builtin_bit_cast(unsigned, pe[3]) << 32)
                            | __builtin_bit_cast(unsigned, pe[2]);
                        __hip_atomic_store((unsigned long long*)pb,       lo, __ATOMIC_RELAXED, __HIP_MEMORY_SCOPE_AGENT);
                        __hip_atomic_store((unsigned long long*)(pb + 2), hi, __ATOMIC_RELAXED, __HIP_MEMORY_SCOPE_AGENT);
                    }
                }
            }
            __syncthreads();   // drain PB/out stores
            if (tid == 0)
                __hip_atomic_store(ffl + (g << 9) + (u << 4), iu1,
                                   __ATOMIC_RELAXED, __HIP_MEMORY_SCOPE_AGENT);
        }

        // ---- epoch: aggregator polls 64 hflags lane-parallel; rest poll epoch ----
        if (ISL1 && u == 0) {
            if (wv == 0) {
                for (;;) {
                    unsigned v = __hip_atomic_load(hfl + (g << 10) + (lane << 4),
                                                   __ATOMIC_RELAXED, __HIP_MEMORY_SCOPE_AGENT);
                    if (__all((int)(v >= iu1))) break;
                    __builtin_amdgcn_s_sleep(1);
                }
                if (lane == 0)
                    __hip_atomic_store(epo + (g << 5), iu1,
                                       __ATOMIC_RELAXED, __HIP_MEMORY_SCOPE_AGENT);
            }
            __syncthreads();
        } else {
            if (wv == 0) {
                while (__hip_atomic_load(epo + (g << 5), __ATOMIC_RELAXED,
                                         __HIP_MEMORY_SCOPE_AGENT) < iu1)
                    __builtin_amdgcn_s_sleep(1);
            }
            __syncthreads();
        }
    }
}

__global__ __launch_bounds__(256, 1) void lstm_mfma(
    const float* __restrict__ x, const float* __restrict__ fc1b,
    const float* __restrict__ fc2w, const float* __restrict__ fc2b,
    char* __restrict__ ws, float* __restrict__ out)
{
    __shared__ __align__(16) char sm[65536];
    const int tid  = threadIdx.x;
    const int lane = tid & 63;
    const int wv   = __builtin_amdgcn_readfirstlane(tid >> 6);
    const int blk  = blockIdx.x;
    const int xcd  = blk & 7, slot = blk >> 3;
    const int g    = xcd >> 1, side = xcd & 1;
    if (slot < 16)
        role<true >(x, fc1b, fc2w, fc2b, ws, out, g, side*16 + slot, false,
                    wv, lane, sm);
    else
        role<false>(x, fc1b, fc2w, fc2b, ws, out, g, side*16 + (slot - 16),
                    (slot == 16) && (side == 0), wv, lane, sm);
}

extern "C" void kernel_launch(void* const* d_in, const int* in_sizes, int n_in,
                              void* d_out, int out_size, void* d_ws, size_t ws_size,
                              hipStream_t stream)
{
    const float* x    = (const float*)d_in[0];
    const float* Wih0 = (const float*)d_in[1];
    const float* Whh0 = (const float*)d_in[2];
    const float* bih0 = (const float*)d_in[3];
    const float* bhh0 = (const float*)d_in[4];
    const float* Wih1 = (const float*)d_in[5];
    const float* Whh1 = (const float*)d_in[6];
    const float* bih1 = (const float*)d_in[7];
    const float* bhh1 = (const float*)d_in[8];
    const float* fc1w = (const float*)d_in[9];
    const float* fc1b = (const float*)d_in[10];
    const float* fc2w = (const float*)d_in[11];
    const float* fc2b = (const float*)d_in[12];
    char*  ws  = (char*)d_ws;
    float* out = (float*)d_out;

    prep_kernel<<<1024, 256, 0, stream>>>(Wih0, Whh0, bih0, bhh0,
                                          Wih1, Whh1, bih1, bhh1, fc1w, ws);

    void* args[] = {(void*)&x, (void*)&fc1b, (void*)&fc2w, (void*)&fc2b,
                    (void*)&ws, (void*)&out};
    hipLaunchCooperativeKernel((const void*)lstm_mfma, dim3(256), dim3(256),
                               args, 0, stream);
}